// Round 3
// baseline (1002.783 us; speedup 1.0000x reference)
//
#include <hip/hip_runtime.h>
#include <cstdint>
#include <cstddef>

// fstgcn on MI355X — round 7:
//  (1) k_zglu FUSED into k_gemm_adj<1> epilogue: t-tile -> LDS (bf16, slot-XOR
//      swizzle) -> in-block xW GEMM (K=64) -> GLU+max -> curT/maxT direct.
//      Kills tbuf 8MiB round-trip per (w,j) and 27 launches. Round-6 budget
//      said non-GEMM shuffle kernels ~ half the runtime.
//  (2) bf16 raw-data mirror `dr` written by k_prepg; k_final reads bf16
//      (halves its read traffic, removes 128 cvts/lane in the MFMA loop).
//  (3) Bank-conflict counter identified as global_load_lds deposit accounting
//      (8 cy/instr minimum) — not a lever; GEMM main loop left as-is.

typedef __bf16 bf16;
typedef float f32x4 __attribute__((ext_vector_type(4)));
typedef __bf16 bf16x8 __attribute__((ext_vector_type(8)));

constexpr int B_  = 32;
constexpr int T_  = 12;
constexpr int N_  = 1024;
constexpr int C_  = 64;
constexpr int NW_ = 9;
constexpr long long SLAB_ = 2048LL * 1024LL;  // 2M elems: one [bc][n] or [b][n][c] slab

// canonical small-weights block (bf16), element offsets
constexpr int OF_ADJ  = 0;            // 1024*4096
constexpr int OF_TEMB = 4194304;      // 768
constexpr int OF_SEMB = 4195072;      // 65536
constexpr int OF_C1W  = 4260608;      // 32768
constexpr int OF_C1B  = 4293376;      // 128
constexpr int OF_GW   = 4293504;      // 221184
constexpr int OF_GB   = 4514688;      // 3456
constexpr int OF_END  = 4518144;

static __device__ __forceinline__ float sigmoidf_(float x) {
  return __builtin_amdgcn_rcpf(1.0f + __expf(-x));
}

// async global->LDS, 16B per lane; lds ptr must be wave-uniform chunk base
static __device__ __forceinline__ void g2l16(const bf16* g, bf16* l) {
  __builtin_amdgcn_global_load_lds(
      (const __attribute__((address_space(1))) void*)g,
      (__attribute__((address_space(3))) void*)l, 16, 0, 0);
}

// ------------------------------------------------------------ dtype detector (insurance)
__global__ __launch_bounds__(256)
void k_detect(const void* __restrict__ data_raw, int* __restrict__ flag)
{
  __shared__ int cnt;
  const int tid = threadIdx.x;
  if (tid == 0) cnt = 0;
  __syncthreads();
  const uint32_t* W = (const uint32_t*)data_raw;
  int local = 0;
  for (int s = 0; s < 32; s++) {
    const uint32_t w = W[tid * 32 + s];
    const int e8 = (int)((w >> 7) & 0xFF);
    local += (e8 < 97 || e8 > 157) ? 1 : 0;
  }
  atomicAdd(&cnt, local);
  __syncthreads();
  if (tid == 0) *flag = (cnt > 2458) ? 1 : 0;     // >30% weird low-half exponent -> fp32
}

static __device__ __forceinline__ float rd_(const void* p, long long i, int isF32) {
  return isF32 ? ((const float*)p)[i] : (float)((const bf16*)p)[i];
}

// ------------------------------------------------------------ canonicalize weights to bf16
__global__ __launch_bounds__(256)
void k_convert(const void* adj, const void* temb, const void* semb,
               const void* c1w, const void* c1b, const void* gw, const void* gb,
               const int* __restrict__ flagp, bf16* __restrict__ canon)
{
  const int isF32 = *flagp;
  const int e = blockIdx.x * 256 + threadIdx.x;
  float v;
  if      (e < OF_TEMB) v = rd_(adj,  e,           isF32);
  else if (e < OF_SEMB) v = rd_(temb, e - OF_TEMB, isF32);
  else if (e < OF_C1W)  v = rd_(semb, e - OF_SEMB, isF32);
  else if (e < OF_C1B)  v = rd_(c1w,  e - OF_C1W,  isF32);
  else if (e < OF_GW)   v = rd_(c1b,  e - OF_C1B,  isF32);
  else if (e < OF_GB)   v = rd_(gw,   e - OF_GW,   isF32);
  else                  v = rd_(gb,   e - OF_GB,   isF32);
  canon[e] = (bf16)v;
}

// ------------------------------------------------------------ prep x slabs (group)
// xg[s][bc][n] = bf16(data[b][tbase+s][n][c] + temb + semb),  bc = b*64+c
// dr (optional): bf16 mirror of raw data, same [b][t][n][c] layout.
__global__ __launch_bounds__(256)
void k_prepg(const void* __restrict__ data_raw, const int* __restrict__ flagp,
             const bf16* __restrict__ temb, const bf16* __restrict__ semb,
             bf16* __restrict__ xg, bf16* __restrict__ dr, int tbase, int wrDr)
{
  const int isF32 = *flagp;
  const int s  = blockIdx.z;
  const int t  = tbase + s;
  const int bc = blockIdx.y * 256 + threadIdx.x;
  const int n0 = blockIdx.x * 128;
  const int b = bc >> 6, c = bc & 63;
  const float te = (float)temb[t * C_ + c];
  const long long dbase = ((long long)(b * T_ + t) * N_) * C_ + c;
  bf16* op = xg + (size_t)s * SLAB_ + (size_t)bc * N_ + n0;
  for (int i = 0; i < 128; i += 8) {
    bf16x8 v;
#pragma unroll
    for (int u = 0; u < 8; u++) {
      const int n = n0 + i + u;
      const float dv = rd_(data_raw, dbase + (long long)n * C_, isF32);
      if (wrDr) dr[dbase + (long long)n * C_] = (bf16)dv;
      v[u] = (bf16)(dv + te + (float)semb[n * C_ + c]);
    }
    *(bf16x8*)&op[i] = v;
  }
}

// ------------------------------------------------------------ weight transposes
__global__ __launch_bounds__(256)
void k_wprep(const bf16* __restrict__ conv1w, const bf16* __restrict__ gcnw,
             bf16* __restrict__ Wt, bf16* __restrict__ gwT)
{
  const int idx = blockIdx.x * 256 + threadIdx.x;
  if (idx < 128 * 256) {               // Wt[c2][kidx], kidx = k*64 + ci
    const int c2 = idx >> 8, kidx = idx & 255;
    const int ci = kidx & 63, k = kidx >> 6;
    Wt[idx] = conv1w[c2 * 256 + ci * 4 + k];
  }
  const int i2 = idx - 128 * 256;
  if (i2 >= 0 && i2 < 27 * 8192) {     // gwT[wj][d][c] = gcn_w[wj][c][d]
    const int wj = i2 >> 13, r = i2 & 8191;
    const int d = r >> 6, c = r & 63;
    gwT[i2] = gcnw[wj * 8192 + c * 128 + d];
  }
}

// ------------------------------------------------------------ adjacency GEMM
// MODE 0 (wing):  init 0,       store fp32 -> outF (Yw)
// MODE 1 (layer): init fp32 Yw, FUSED epilogue: t-tile -> LDS -> xW GEMM
//                 (K=64) -> +bias -> GLU -> curT (bf16, j<2) / maxT (fp32).
template<int MODE>
__global__ __launch_bounds__(256)
void k_gemm_adj(const bf16* __restrict__ Aadj, const bf16* __restrict__ Bop,
                const float* __restrict__ initY, float* __restrict__ outF,
                const bf16* __restrict__ gwT, const bf16* __restrict__ gcnb,
                bf16* __restrict__ curT, float* __restrict__ maxT,
                int Ksize, int jlayer, int wbase)
{
  const int lw = blockIdx.z;
  const int m0 = blockIdx.y * 128;     // n_out tile
  const int c0 = blockIdx.x * 128;     // bc tile
  const int tid = threadIdx.x;
  const int lane = tid & 63, wid = tid >> 6;
  const int lrow = lane & 15, q = lane >> 4;
  const int wm = wid >> 1, wn = wid & 1;

  // single LDS pool: main loop A dbuf [2][4096] at 0, B dbuf at 8192;
  // fused epilogue reuses all 32 KB as the t tile [m 128][bc 128] bf16.
  __shared__ __align__(16) bf16 lsAll[16384];

  // staging source coords (per-lane constants)
  const int srow = lane >> 2;                                    // row in 16-row chunk
  const int sl_w = ((lane >> 2) & 3) ^ ((lane >> 4) & 3);        // s(row) for writes
  const int skel = ((lane & 3) ^ sl_w) * 8;                      // swizzled src k-elem

  // read-side swizzle (per-lane constant)
  const int sl_r  = (lrow & 3) ^ (lrow >> 2);                    // s(row) for reads
  const int rdoff = ((q ^ sl_r) & 3) * 8;                        // swizzled k-elem in row

  const bf16* Bw = Bop + (size_t)lw * SLAB_;

  auto STAGE = [&](int buf, int k0) {
    const int tblk = k0 >> 10;
    const int kloc = k0 & 1023;
    const bf16* Bt = Bw + (size_t)tblk * SLAB_ + kloc;
    const bf16* At = Aadj + k0;
#pragma unroll
    for (int s = 0; s < 2; s++) {
      const int ch  = s * 4 + wid;               // chunk 0..7 (wave-uniform)
      const int row = ch * 16 + srow;
      g2l16(&At[(size_t)(m0 + row) * 4096 + skel], &lsAll[buf * 4096 + ch * 512]);
      g2l16(&Bt[(size_t)(c0 + row) * N_   + skel], &lsAll[8192 + buf * 4096 + ch * 512]);
    }
  };

  // prologue: stage tile 0; overlap acc init with its latency
  STAGE(0, 0);

  f32x4 acc[4][4];
  const size_t woff = (size_t)lw * SLAB_;
  if (MODE == 1) {
#pragma unroll
    for (int i = 0; i < 4; i++)
#pragma unroll
      for (int jj = 0; jj < 4; jj++) {
        const int col = c0 + wn * 64 + jj * 16 + lrow;
        const int b = col >> 6, c = col & 63;
        const float* yp = initY + woff + (size_t)b * (N_ * C_)
                        + (size_t)(m0 + wm * 64 + i * 16 + q * 4) * C_ + c;
#pragma unroll
        for (int r = 0; r < 4; r++) acc[i][jj][r] = yp[(size_t)r * C_];
      }
  } else {
#pragma unroll
    for (int i = 0; i < 4; i++)
#pragma unroll
      for (int jj = 0; jj < 4; jj++)
#pragma unroll
        for (int r = 0; r < 4; r++) acc[i][jj][r] = 0.0f;
  }

  __syncthreads();

  int cur = 0;
  for (int k0 = 0; k0 < Ksize; k0 += 32) {
    if (k0 + 32 < Ksize) STAGE(cur ^ 1, k0 + 32);

    bf16x8 af[4], bfv[4];
#pragma unroll
    for (int i = 0; i < 4; i++)
      af[i]  = *(const bf16x8*)&lsAll[cur * 4096 + (wm * 64 + i * 16 + lrow) * 32 + rdoff];
#pragma unroll
    for (int jj = 0; jj < 4; jj++)
      bfv[jj] = *(const bf16x8*)&lsAll[8192 + cur * 4096 + (wn * 64 + jj * 16 + lrow) * 32 + rdoff];
#pragma unroll
    for (int i = 0; i < 4; i++)
#pragma unroll
      for (int jj = 0; jj < 4; jj++)
        acc[i][jj] = __builtin_amdgcn_mfma_f32_16x16x32_bf16(af[i], bfv[jj], acc[i][jj], 0, 0, 0);

    __syncthreads();
    cur ^= 1;
  }

  if (MODE == 0) {
#pragma unroll
    for (int i = 0; i < 4; i++)
#pragma unroll
      for (int jj = 0; jj < 4; jj++) {
        const int col = c0 + wn * 64 + jj * 16 + lrow;
        const int b = col >> 6, c = col & 63;
        const size_t base = woff + (size_t)b * (N_ * C_)
                          + (size_t)(m0 + wm * 64 + i * 16 + q * 4) * C_ + c;
#pragma unroll
        for (int r = 0; r < 4; r++) outF[base + (size_t)r * C_] = acc[i][jj][r];
      }
    return;
  }

  // ================= fused epilogue (MODE 1) =================
  // t tile [m 128][bc 128] bf16 in LDS. Row = 256 B = 16 slots of 16 B.
  // Swizzle: low-3 slot bits ^= g(row), g(r) = (r ^ (r>>3)) & 7 (bijective,
  // same formula both sides; plain ds ops so rule-21 linear-dest constraint
  // doesn't apply).
  char* tls = (char*)lsAll;
#pragma unroll
  for (int i = 0; i < 4; i++)
#pragma unroll
    for (int jj = 0; jj < 4; jj++) {
      const int bc = wn * 64 + jj * 16 + lrow;
#pragma unroll
      for (int r = 0; r < 4; r++) {
        const int m = wm * 64 + i * 16 + q * 4 + r;
        const int byte = m * 256 + ((bc * 2) ^ (((m ^ (m >> 3)) & 7) << 4));
        *(bf16*)(tls + byte) = (bf16)acc[i][jj][r];
      }
    }
  __syncthreads();

  const int wj = (wbase + lw) * 3 + jlayer;
  const bf16* Agw  = gwT  + (size_t)wj * 8192;   // [d 128][c 64]
  const bf16* bias = gcnb + (size_t)wj * 128;
  const int nloc0 = wid * 32;                    // per-wave n strip (local)

#pragma unroll
  for (int bl = 0; bl < 2; bl++) {               // two b's in this bc tile
    f32x4 acc2[8][2];
#pragma unroll
    for (int rt = 0; rt < 8; rt++)
#pragma unroll
      for (int ct = 0; ct < 2; ct++)
#pragma unroll
        for (int r = 0; r < 4; r++) acc2[rt][ct][r] = 0.0f;

#pragma unroll
    for (int ks = 0; ks < 2; ks++) {
      bf16x8 bv[2];
#pragma unroll
      for (int ct = 0; ct < 2; ct++) {
        const int nl = nloc0 + ct * 16 + lrow;
        const int byte = nl * 256 +
          (((bl * 64 + ks * 32 + q * 8) * 2) ^ (((nl ^ (nl >> 3)) & 7) << 4));
        bv[ct] = *(const bf16x8*)(tls + byte);
      }
#pragma unroll
      for (int rt = 0; rt < 8; rt++) {
        const bf16x8 av = *(const bf16x8*)&Agw[(rt * 16 + lrow) * 64 + ks * 32 + q * 8];
#pragma unroll
        for (int ct = 0; ct < 2; ct++)
          acc2[rt][ct] = __builtin_amdgcn_mfma_f32_16x16x32_bf16(av, bv[ct], acc2[rt][ct], 0, 0, 0);
      }
    }

    const int bg = (c0 >> 6) + bl;
#pragma unroll
    for (int rt = 0; rt < 4; rt++)
#pragma unroll
      for (int ct = 0; ct < 2; ct++) {
        const int n = m0 + nloc0 + ct * 16 + lrow;
#pragma unroll
        for (int r = 0; r < 4; r++) {
          const int d = rt * 16 + q * 4 + r;
          const float zL = acc2[rt][ct][r]     + (float)bias[d];
          const float zR = acc2[rt + 4][ct][r] + (float)bias[d + 64];
          const float cv = zL * sigmoidf_(zR);
          const size_t addr = woff + (size_t)(bg * 64 + d) * N_ + n;
          if (jlayer < 2) curT[addr] = (bf16)cv;   // j==2 curT is dead
          if (jlayer == 0) maxT[addr] = cv;
          else             maxT[addr] = fmaxf(maxT[addr], cv);
        }
      }
  }
}

// ------------------------------------------------------------ conv GEMM + GLU + max add
__global__ __launch_bounds__(256)
void k_final(const void* __restrict__ data_raw, const int* __restrict__ flagp,
             const bf16* __restrict__ dr,
             const bf16* __restrict__ Wt, const bf16* __restrict__ convb,
             const float* __restrict__ maxT, float* __restrict__ out, int wbase)
{
  const int isF32 = *flagp;
  const int useDr = dr != nullptr;
  const int lw = blockIdx.z;
  const int w = wbase + lw;
  const int bbat = blockIdx.y;
  const int tid = threadIdx.x;
  const int lane = tid & 63, wid = tid >> 6;
  const int lrow = lane & 15, q = lane >> 4;
  const int n0 = blockIdx.x * 128 + wid * 32;

  f32x4 acc[2][8];
#pragma unroll
  for (int rt = 0; rt < 2; rt++)
#pragma unroll
    for (int ct = 0; ct < 8; ct++)
#pragma unroll
      for (int r = 0; r < 4; r++) acc[rt][ct][r] = 0.0f;

#pragma unroll
  for (int s = 0; s < 8; s++) {                 // kidx = s*32 + q*8 + u = k*64 + ci
    const int k = s >> 1, ci0 = (s & 1) * 32;
    bf16x8 av[2];
#pragma unroll
    for (int rt = 0; rt < 2; rt++) {
      const long long off =
        ((long long)((bbat * T_ + w + k) * N_) + n0 + rt * 16 + lrow) * C_ + ci0 + q * 8;
      if (useDr) {
        av[rt] = *(const bf16x8*)&dr[off];
      } else if (!isF32) {
        av[rt] = *(const bf16x8*)&((const bf16*)data_raw)[off];
      } else {
        const float* p = (const float*)data_raw + off;
        const f32x4 v0 = *(const f32x4*)p;
        const f32x4 v1 = *(const f32x4*)(p + 4);
        bf16x8 v;
#pragma unroll
        for (int u = 0; u < 4; u++) { v[u] = (bf16)v0[u]; v[u + 4] = (bf16)v1[u]; }
        av[rt] = v;
      }
    }
#pragma unroll
    for (int ct = 0; ct < 8; ct++) {
      const bf16x8 bv = *(const bf16x8*)&Wt[(ct * 16 + lrow) * 256 + s * 32 + q * 8];
#pragma unroll
      for (int rt = 0; rt < 2; rt++)
        acc[rt][ct] = __builtin_amdgcn_mfma_f32_16x16x32_bf16(av[rt], bv, acc[rt][ct], 0, 0, 0);
    }
  }

#pragma unroll
  for (int rt = 0; rt < 2; rt++)
#pragma unroll
    for (int ctL = 0; ctL < 4; ctL++) {
      const int cL = ctL * 16 + lrow;
      const float bL = (float)convb[cL], bR = (float)convb[cL + 64];
#pragma unroll
      for (int r = 0; r < 4; r++) {
        const int n = n0 + rt * 16 + q * 4 + r;
        const float zL = acc[rt][ctL][r] + bL;
        const float zR = acc[rt][ctL + 4][r] + bR;
        const float res = sigmoidf_(zL) * zR;
        const float mv = maxT[(size_t)lw * SLAB_ + (size_t)(bbat * 64 + cL) * N_ + n];
        out[(size_t)((bbat * NW_ + w) * N_ + n) * C_ + cL] = res + mv;
      }
    }
}

// ------------------------------------------------------------ launcher
extern "C" void kernel_launch(void* const* d_in, const int* in_sizes, int n_in,
                              void* d_out, int out_size, void* d_ws, size_t ws_size,
                              hipStream_t stream)
{
  (void)in_sizes; (void)n_in; (void)out_size;
  const void* data   = d_in[1];
  const void* adj    = d_in[2];
  const void* temb   = d_in[3];
  const void* semb   = d_in[4];
  const void* conv1w = d_in[5];
  const void* conv1b = d_in[6];
  const void* gcnw   = d_in[7];
  const void* gcnb   = d_in[8];
  float* out = (float*)d_out;   // fp32 output per reference dtype

  const size_t DRBYTES = (size_t)B_ * T_ * N_ * C_ * 2;   // 48 MiB

  // footprint(G, withDr): canon + xg + Yw + curT + maxT + Wt + gwT [+ dr]
  auto fp = [&](int g, int withdr) -> size_t {
    size_t need = 256;
    auto pad = [&](size_t x) { need += (x + 255) & ~(size_t)255; };
    pad((size_t)OF_END * 2);
    pad((size_t)(g + 3) * SLAB_ * 2);     // xg
    pad((size_t)g * SLAB_ * 4);           // Yw (fp32)
    pad((size_t)g * SLAB_ * 2);           // curT
    pad((size_t)g * SLAB_ * 4);           // maxT (fp32)
    pad(128 * 256 * 2);                   // Wt
    pad(27 * 8192 * 2);                   // gwT
    if (withdr) pad(DRBYTES);
    return need;
  };

  int G = 1;
  for (int g = 9; g >= 2; g--) if (fp(g, 0) <= ws_size) { G = g; break; }
  const int useDr = fp(G, 1) <= ws_size ? 1 : 0;

  char* ws = (char*)d_ws;
  int* flag = (int*)ws;
  size_t off = 256;
  auto allocB = [&](size_t bytes) -> char* {
    char* p = ws + off;
    off += (bytes + 255) & ~(size_t)255;
    return p;
  };
  bf16*  canon = (bf16*) allocB((size_t)OF_END * 2);
  bf16*  xg    = (bf16*) allocB((size_t)(G + 3) * SLAB_ * 2);
  float* Yw    = (float*)allocB((size_t)G * SLAB_ * 4);
  bf16*  curT  = (bf16*) allocB((size_t)G * SLAB_ * 2);
  float* maxT  = (float*)allocB((size_t)G * SLAB_ * 4);
  bf16*  Wt    = (bf16*) allocB(128 * 256 * 2);
  bf16*  gwT   = (bf16*) allocB(27 * 8192 * 2);
  bf16*  dr    = useDr ? (bf16*)allocB(DRBYTES) : nullptr;

  const bf16* adjC  = canon + OF_ADJ;
  const bf16* tembC = canon + OF_TEMB;
  const bf16* sembC = canon + OF_SEMB;
  const bf16* c1wC  = canon + OF_C1W;
  const bf16* c1bC  = canon + OF_C1B;
  const bf16* gwC   = canon + OF_GW;
  const bf16* gbC   = canon + OF_GB;

  k_detect<<<dim3(1), 256, 0, stream>>>(data, flag);
  k_convert<<<dim3(OF_END / 256), 256, 0, stream>>>(adj, temb, semb, conv1w, conv1b,
                                                    gcnw, gcnb, flag, canon);
  k_wprep<<<dim3(992), 256, 0, stream>>>(c1wC, gwC, Wt, gwT);

  for (int wbase = 0; wbase < NW_; wbase += G) {
    const int gc = (NW_ - wbase < G) ? (NW_ - wbase) : G;

    k_prepg<<<dim3(8, 8, gc + 3), 256, 0, stream>>>(data, flag, tembC, sembC,
                                                    xg, dr, wbase, useDr);

    // wing: Yw = adj[:, :3N] @ x[w..w+3)   (fp32 out)
    k_gemm_adj<0><<<dim3(16, 8, gc), 256, 0, stream>>>(
        adjC, xg, nullptr, Yw, nullptr, nullptr, nullptr, nullptr, 3072, 0, 0);

    for (int j = 0; j < 3; j++) {
      const bf16* Bop = (j == 0) ? (xg + 3 * SLAB_) : curT;
      k_gemm_adj<1><<<dim3(16, 8, gc), 256, 0, stream>>>(
          adjC + 3072, Bop, Yw, nullptr, gwT, gbC, curT, maxT, 1024, j, wbase);
    }

    k_final<<<dim3(8, 32, gc), 256, 0, stream>>>(data, flag, dr, Wt, c1bC, maxT, out, wbase);
  }
}

// Round 4
// 917.432 us; speedup vs baseline: 1.0930x; 1.0930x over previous
//
#include <hip/hip_runtime.h>
#include <cstdint>
#include <cstddef>

// fstgcn on MI355X — round 8:
//  (1) k_prepg rebuilt: dr mirror DROPPED (round-7 counters: FETCH 49MB for a
//      100MB input => data is L3-resident, dr bought nothing, cost ~55us);
//      grid 768->3072 blocks (occupancy 33%->~full); semb strip staged in LDS
//      (was 128 stride-128B scalar loads/thread).
//  (2) k_final reverted to direct fp32 reads (L3-resident).
//  (3) zglu fusion kept (round-7 regression fully attributed to prepg/dr).

typedef __bf16 bf16;
typedef float f32x4 __attribute__((ext_vector_type(4)));
typedef __bf16 bf16x8 __attribute__((ext_vector_type(8)));

constexpr int B_  = 32;
constexpr int T_  = 12;
constexpr int N_  = 1024;
constexpr int C_  = 64;
constexpr int NW_ = 9;
constexpr long long SLAB_ = 2048LL * 1024LL;  // 2M elems: one [bc][n] or [b][n][c] slab

// canonical small-weights block (bf16), element offsets
constexpr int OF_ADJ  = 0;            // 1024*4096
constexpr int OF_TEMB = 4194304;      // 768
constexpr int OF_SEMB = 4195072;      // 65536
constexpr int OF_C1W  = 4260608;      // 32768
constexpr int OF_C1B  = 4293376;      // 128
constexpr int OF_GW   = 4293504;      // 221184
constexpr int OF_GB   = 4514688;      // 3456
constexpr int OF_END  = 4518144;

static __device__ __forceinline__ float sigmoidf_(float x) {
  return __builtin_amdgcn_rcpf(1.0f + __expf(-x));
}

// async global->LDS, 16B per lane; lds ptr must be wave-uniform chunk base
static __device__ __forceinline__ void g2l16(const bf16* g, bf16* l) {
  __builtin_amdgcn_global_load_lds(
      (const __attribute__((address_space(1))) void*)g,
      (__attribute__((address_space(3))) void*)l, 16, 0, 0);
}

// ------------------------------------------------------------ dtype detector (insurance)
__global__ __launch_bounds__(256)
void k_detect(const void* __restrict__ data_raw, int* __restrict__ flag)
{
  __shared__ int cnt;
  const int tid = threadIdx.x;
  if (tid == 0) cnt = 0;
  __syncthreads();
  const uint32_t* W = (const uint32_t*)data_raw;
  int local = 0;
  for (int s = 0; s < 32; s++) {
    const uint32_t w = W[tid * 32 + s];
    const int e8 = (int)((w >> 7) & 0xFF);
    local += (e8 < 97 || e8 > 157) ? 1 : 0;
  }
  atomicAdd(&cnt, local);
  __syncthreads();
  if (tid == 0) *flag = (cnt > 2458) ? 1 : 0;     // >30% weird low-half exponent -> fp32
}

static __device__ __forceinline__ float rd_(const void* p, long long i, int isF32) {
  return isF32 ? ((const float*)p)[i] : (float)((const bf16*)p)[i];
}

// ------------------------------------------------------------ canonicalize weights to bf16
__global__ __launch_bounds__(256)
void k_convert(const void* adj, const void* temb, const void* semb,
               const void* c1w, const void* c1b, const void* gw, const void* gb,
               const int* __restrict__ flagp, bf16* __restrict__ canon)
{
  const int isF32 = *flagp;
  const int e = blockIdx.x * 256 + threadIdx.x;
  float v;
  if      (e < OF_TEMB) v = rd_(adj,  e,           isF32);
  else if (e < OF_SEMB) v = rd_(temb, e - OF_TEMB, isF32);
  else if (e < OF_C1W)  v = rd_(semb, e - OF_SEMB, isF32);
  else if (e < OF_C1B)  v = rd_(c1w,  e - OF_C1W,  isF32);
  else if (e < OF_GW)   v = rd_(c1b,  e - OF_C1B,  isF32);
  else if (e < OF_GB)   v = rd_(gw,   e - OF_GW,   isF32);
  else                  v = rd_(gb,   e - OF_GB,   isF32);
  canon[e] = (bf16)v;
}

// ------------------------------------------------------------ prep x slabs (group)
// xg[s][bc][n] = bf16(data[b][tbase+s][n][c] + temb + semb),  bc = b*64+c
// 32-n strips, semb strip staged in LDS. Grid (32, 8, NS) = up to 3072 blocks.
__global__ __launch_bounds__(256)
void k_prepg(const void* __restrict__ data_raw, const int* __restrict__ flagp,
             const bf16* __restrict__ temb, const bf16* __restrict__ semb,
             bf16* __restrict__ xg, int tbase)
{
  const int isF32 = *flagp;
  const int s  = blockIdx.z;
  const int t  = tbase + s;
  const int n0 = blockIdx.x * 32;
  const int bc = blockIdx.y * 256 + threadIdx.x;
  const int b = bc >> 6, c = bc & 63;

  __shared__ bf16 lsS[32 * 64];        // semb strip [n 32][c 64]
  *(bf16x8*)&lsS[threadIdx.x * 8] = *(const bf16x8*)&semb[n0 * C_ + threadIdx.x * 8];
  __syncthreads();

  const float te = (float)temb[t * C_ + c];
  const long long dbase = ((long long)(b * T_ + t) * N_ + n0) * C_ + c;
  bf16* op = xg + (size_t)s * SLAB_ + (size_t)bc * N_ + n0;
#pragma unroll
  for (int i = 0; i < 32; i += 8) {
    bf16x8 v;
#pragma unroll
    for (int u = 0; u < 8; u++) {
      const int n = i + u;
      const float dv = rd_(data_raw, dbase + (long long)n * C_, isF32);
      v[u] = (bf16)(dv + te + (float)lsS[n * C_ + c]);
    }
    *(bf16x8*)&op[i] = v;
  }
}

// ------------------------------------------------------------ weight transposes
__global__ __launch_bounds__(256)
void k_wprep(const bf16* __restrict__ conv1w, const bf16* __restrict__ gcnw,
             bf16* __restrict__ Wt, bf16* __restrict__ gwT)
{
  const int idx = blockIdx.x * 256 + threadIdx.x;
  if (idx < 128 * 256) {               // Wt[c2][kidx], kidx = k*64 + ci
    const int c2 = idx >> 8, kidx = idx & 255;
    const int ci = kidx & 63, k = kidx >> 6;
    Wt[idx] = conv1w[c2 * 256 + ci * 4 + k];
  }
  const int i2 = idx - 128 * 256;
  if (i2 >= 0 && i2 < 27 * 8192) {     // gwT[wj][d][c] = gcn_w[wj][c][d]
    const int wj = i2 >> 13, r = i2 & 8191;
    const int d = r >> 6, c = r & 63;
    gwT[i2] = gcnw[wj * 8192 + c * 128 + d];
  }
}

// ------------------------------------------------------------ adjacency GEMM
// MODE 0 (wing):  init 0,       store fp32 -> outF (Yw)
// MODE 1 (layer): init fp32 Yw, FUSED epilogue: t-tile -> LDS -> xW GEMM
//                 (K=64) -> +bias -> GLU -> curT (bf16, j<2) / maxT (fp32).
template<int MODE>
__global__ __launch_bounds__(256)
void k_gemm_adj(const bf16* __restrict__ Aadj, const bf16* __restrict__ Bop,
                const float* __restrict__ initY, float* __restrict__ outF,
                const bf16* __restrict__ gwT, const bf16* __restrict__ gcnb,
                bf16* __restrict__ curT, float* __restrict__ maxT,
                int Ksize, int jlayer, int wbase)
{
  const int lw = blockIdx.z;
  const int m0 = blockIdx.y * 128;     // n_out tile
  const int c0 = blockIdx.x * 128;     // bc tile
  const int tid = threadIdx.x;
  const int lane = tid & 63, wid = tid >> 6;
  const int lrow = lane & 15, q = lane >> 4;
  const int wm = wid >> 1, wn = wid & 1;

  // single LDS pool: main loop A dbuf [2][4096] at 0, B dbuf at 8192;
  // fused epilogue reuses all 32 KB as the t tile [m 128][bc 128] bf16.
  __shared__ __align__(16) bf16 lsAll[16384];

  // staging source coords (per-lane constants)
  const int srow = lane >> 2;                                    // row in 16-row chunk
  const int sl_w = ((lane >> 2) & 3) ^ ((lane >> 4) & 3);        // s(row) for writes
  const int skel = ((lane & 3) ^ sl_w) * 8;                      // swizzled src k-elem

  // read-side swizzle (per-lane constant)
  const int sl_r  = (lrow & 3) ^ (lrow >> 2);                    // s(row) for reads
  const int rdoff = ((q ^ sl_r) & 3) * 8;                        // swizzled k-elem in row

  const bf16* Bw = Bop + (size_t)lw * SLAB_;

  auto STAGE = [&](int buf, int k0) {
    const int tblk = k0 >> 10;
    const int kloc = k0 & 1023;
    const bf16* Bt = Bw + (size_t)tblk * SLAB_ + kloc;
    const bf16* At = Aadj + k0;
#pragma unroll
    for (int s = 0; s < 2; s++) {
      const int ch  = s * 4 + wid;               // chunk 0..7 (wave-uniform)
      const int row = ch * 16 + srow;
      g2l16(&At[(size_t)(m0 + row) * 4096 + skel], &lsAll[buf * 4096 + ch * 512]);
      g2l16(&Bt[(size_t)(c0 + row) * N_   + skel], &lsAll[8192 + buf * 4096 + ch * 512]);
    }
  };

  // prologue: stage tile 0; overlap acc init with its latency
  STAGE(0, 0);

  f32x4 acc[4][4];
  const size_t woff = (size_t)lw * SLAB_;
  if (MODE == 1) {
#pragma unroll
    for (int i = 0; i < 4; i++)
#pragma unroll
      for (int jj = 0; jj < 4; jj++) {
        const int col = c0 + wn * 64 + jj * 16 + lrow;
        const int b = col >> 6, c = col & 63;
        const float* yp = initY + woff + (size_t)b * (N_ * C_)
                        + (size_t)(m0 + wm * 64 + i * 16 + q * 4) * C_ + c;
#pragma unroll
        for (int r = 0; r < 4; r++) acc[i][jj][r] = yp[(size_t)r * C_];
      }
  } else {
#pragma unroll
    for (int i = 0; i < 4; i++)
#pragma unroll
      for (int jj = 0; jj < 4; jj++)
#pragma unroll
        for (int r = 0; r < 4; r++) acc[i][jj][r] = 0.0f;
  }

  __syncthreads();

  int cur = 0;
  for (int k0 = 0; k0 < Ksize; k0 += 32) {
    if (k0 + 32 < Ksize) STAGE(cur ^ 1, k0 + 32);

    bf16x8 af[4], bfv[4];
#pragma unroll
    for (int i = 0; i < 4; i++)
      af[i]  = *(const bf16x8*)&lsAll[cur * 4096 + (wm * 64 + i * 16 + lrow) * 32 + rdoff];
#pragma unroll
    for (int jj = 0; jj < 4; jj++)
      bfv[jj] = *(const bf16x8*)&lsAll[8192 + cur * 4096 + (wn * 64 + jj * 16 + lrow) * 32 + rdoff];
#pragma unroll
    for (int i = 0; i < 4; i++)
#pragma unroll
      for (int jj = 0; jj < 4; jj++)
        acc[i][jj] = __builtin_amdgcn_mfma_f32_16x16x32_bf16(af[i], bfv[jj], acc[i][jj], 0, 0, 0);

    __syncthreads();
    cur ^= 1;
  }

  if (MODE == 0) {
#pragma unroll
    for (int i = 0; i < 4; i++)
#pragma unroll
      for (int jj = 0; jj < 4; jj++) {
        const int col = c0 + wn * 64 + jj * 16 + lrow;
        const int b = col >> 6, c = col & 63;
        const size_t base = woff + (size_t)b * (N_ * C_)
                          + (size_t)(m0 + wm * 64 + i * 16 + q * 4) * C_ + c;
#pragma unroll
        for (int r = 0; r < 4; r++) outF[base + (size_t)r * C_] = acc[i][jj][r];
      }
    return;
  }

  // ================= fused epilogue (MODE 1) =================
  // t tile [m 128][bc 128] bf16 in LDS. Row = 256 B = 16 slots of 16 B.
  // Swizzle: low-3 slot bits ^= g(row), g(r) = (r ^ (r>>3)) & 7 (bijective,
  // same formula both sides; plain ds ops so rule-21 linear-dest constraint
  // doesn't apply).
  char* tls = (char*)lsAll;
#pragma unroll
  for (int i = 0; i < 4; i++)
#pragma unroll
    for (int jj = 0; jj < 4; jj++) {
      const int bc = wn * 64 + jj * 16 + lrow;
#pragma unroll
      for (int r = 0; r < 4; r++) {
        const int m = wm * 64 + i * 16 + q * 4 + r;
        const int byte = m * 256 + ((bc * 2) ^ (((m ^ (m >> 3)) & 7) << 4));
        *(bf16*)(tls + byte) = (bf16)acc[i][jj][r];
      }
    }
  __syncthreads();

  const int wj = (wbase + lw) * 3 + jlayer;
  const bf16* Agw  = gwT  + (size_t)wj * 8192;   // [d 128][c 64]
  const bf16* bias = gcnb + (size_t)wj * 128;
  const int nloc0 = wid * 32;                    // per-wave n strip (local)

#pragma unroll
  for (int bl = 0; bl < 2; bl++) {               // two b's in this bc tile
    f32x4 acc2[8][2];
#pragma unroll
    for (int rt = 0; rt < 8; rt++)
#pragma unroll
      for (int ct = 0; ct < 2; ct++)
#pragma unroll
        for (int r = 0; r < 4; r++) acc2[rt][ct][r] = 0.0f;

#pragma unroll
    for (int ks = 0; ks < 2; ks++) {
      bf16x8 bv[2];
#pragma unroll
      for (int ct = 0; ct < 2; ct++) {
        const int nl = nloc0 + ct * 16 + lrow;
        const int byte = nl * 256 +
          (((bl * 64 + ks * 32 + q * 8) * 2) ^ (((nl ^ (nl >> 3)) & 7) << 4));
        bv[ct] = *(const bf16x8*)(tls + byte);
      }
#pragma unroll
      for (int rt = 0; rt < 8; rt++) {
        const bf16x8 av = *(const bf16x8*)&Agw[(rt * 16 + lrow) * 64 + ks * 32 + q * 8];
#pragma unroll
        for (int ct = 0; ct < 2; ct++)
          acc2[rt][ct] = __builtin_amdgcn_mfma_f32_16x16x32_bf16(av, bv[ct], acc2[rt][ct], 0, 0, 0);
      }
    }

    const int bg = (c0 >> 6) + bl;
#pragma unroll
    for (int rt = 0; rt < 4; rt++)
#pragma unroll
      for (int ct = 0; ct < 2; ct++) {
        const int n = m0 + nloc0 + ct * 16 + lrow;
#pragma unroll
        for (int r = 0; r < 4; r++) {
          const int d = rt * 16 + q * 4 + r;
          const float zL = acc2[rt][ct][r]     + (float)bias[d];
          const float zR = acc2[rt + 4][ct][r] + (float)bias[d + 64];
          const float cv = zL * sigmoidf_(zR);
          const size_t addr = woff + (size_t)(bg * 64 + d) * N_ + n;
          if (jlayer < 2) curT[addr] = (bf16)cv;   // j==2 curT is dead
          if (jlayer == 0) maxT[addr] = cv;
          else             maxT[addr] = fmaxf(maxT[addr], cv);
        }
      }
  }
}

// ------------------------------------------------------------ conv GEMM + GLU + max add
__global__ __launch_bounds__(256)
void k_final(const void* __restrict__ data_raw, const int* __restrict__ flagp,
             const bf16* __restrict__ Wt, const bf16* __restrict__ convb,
             const float* __restrict__ maxT, float* __restrict__ out, int wbase)
{
  const int isF32 = *flagp;
  const int lw = blockIdx.z;
  const int w = wbase + lw;
  const int bbat = blockIdx.y;
  const int tid = threadIdx.x;
  const int lane = tid & 63, wid = tid >> 6;
  const int lrow = lane & 15, q = lane >> 4;
  const int n0 = blockIdx.x * 128 + wid * 32;

  f32x4 acc[2][8];
#pragma unroll
  for (int rt = 0; rt < 2; rt++)
#pragma unroll
    for (int ct = 0; ct < 8; ct++)
#pragma unroll
      for (int r = 0; r < 4; r++) acc[rt][ct][r] = 0.0f;

#pragma unroll
  for (int s = 0; s < 8; s++) {                 // kidx = s*32 + q*8 + u = k*64 + ci
    const int k = s >> 1, ci0 = (s & 1) * 32;
    bf16x8 av[2];
#pragma unroll
    for (int rt = 0; rt < 2; rt++) {
      const long long off =
        ((long long)((bbat * T_ + w + k) * N_) + n0 + rt * 16 + lrow) * C_ + ci0 + q * 8;
      if (!isF32) {
        av[rt] = *(const bf16x8*)&((const bf16*)data_raw)[off];
      } else {
        const float* p = (const float*)data_raw + off;
        const f32x4 v0 = *(const f32x4*)p;
        const f32x4 v1 = *(const f32x4*)(p + 4);
        bf16x8 v;
#pragma unroll
        for (int u = 0; u < 4; u++) { v[u] = (bf16)v0[u]; v[u + 4] = (bf16)v1[u]; }
        av[rt] = v;
      }
    }
#pragma unroll
    for (int ct = 0; ct < 8; ct++) {
      const bf16x8 bv = *(const bf16x8*)&Wt[(ct * 16 + lrow) * 256 + s * 32 + q * 8];
#pragma unroll
      for (int rt = 0; rt < 2; rt++)
        acc[rt][ct] = __builtin_amdgcn_mfma_f32_16x16x32_bf16(av[rt], bv, acc[rt][ct], 0, 0, 0);
    }
  }

#pragma unroll
  for (int rt = 0; rt < 2; rt++)
#pragma unroll
    for (int ctL = 0; ctL < 4; ctL++) {
      const int cL = ctL * 16 + lrow;
      const float bL = (float)convb[cL], bR = (float)convb[cL + 64];
#pragma unroll
      for (int r = 0; r < 4; r++) {
        const int n = n0 + rt * 16 + q * 4 + r;
        const float zL = acc[rt][ctL][r] + bL;
        const float zR = acc[rt][ctL + 4][r] + bR;
        const float res = sigmoidf_(zL) * zR;
        const float mv = maxT[(size_t)lw * SLAB_ + (size_t)(bbat * 64 + cL) * N_ + n];
        out[(size_t)((bbat * NW_ + w) * N_ + n) * C_ + cL] = res + mv;
      }
    }
}

// ------------------------------------------------------------ launcher
extern "C" void kernel_launch(void* const* d_in, const int* in_sizes, int n_in,
                              void* d_out, int out_size, void* d_ws, size_t ws_size,
                              hipStream_t stream)
{
  (void)in_sizes; (void)n_in; (void)out_size;
  const void* data   = d_in[1];
  const void* adj    = d_in[2];
  const void* temb   = d_in[3];
  const void* semb   = d_in[4];
  const void* conv1w = d_in[5];
  const void* conv1b = d_in[6];
  const void* gcnw   = d_in[7];
  const void* gcnb   = d_in[8];
  float* out = (float*)d_out;   // fp32 output per reference dtype

  // footprint(G): canon + xg + Yw + curT + maxT + Wt + gwT
  auto fp = [&](int g) -> size_t {
    size_t need = 256;
    auto pad = [&](size_t x) { need += (x + 255) & ~(size_t)255; };
    pad((size_t)OF_END * 2);
    pad((size_t)(g + 3) * SLAB_ * 2);     // xg
    pad((size_t)g * SLAB_ * 4);           // Yw (fp32)
    pad((size_t)g * SLAB_ * 2);           // curT
    pad((size_t)g * SLAB_ * 4);           // maxT (fp32)
    pad(128 * 256 * 2);                   // Wt
    pad(27 * 8192 * 2);                   // gwT
    return need;
  };

  int G = 1;
  for (int g = 9; g >= 2; g--) if (fp(g) <= ws_size) { G = g; break; }

  char* ws = (char*)d_ws;
  int* flag = (int*)ws;
  size_t off = 256;
  auto allocB = [&](size_t bytes) -> char* {
    char* p = ws + off;
    off += (bytes + 255) & ~(size_t)255;
    return p;
  };
  bf16*  canon = (bf16*) allocB((size_t)OF_END * 2);
  bf16*  xg    = (bf16*) allocB((size_t)(G + 3) * SLAB_ * 2);
  float* Yw    = (float*)allocB((size_t)G * SLAB_ * 4);
  bf16*  curT  = (bf16*) allocB((size_t)G * SLAB_ * 2);
  float* maxT  = (float*)allocB((size_t)G * SLAB_ * 4);
  bf16*  Wt    = (bf16*) allocB(128 * 256 * 2);
  bf16*  gwT   = (bf16*) allocB(27 * 8192 * 2);

  const bf16* adjC  = canon + OF_ADJ;
  const bf16* tembC = canon + OF_TEMB;
  const bf16* sembC = canon + OF_SEMB;
  const bf16* c1wC  = canon + OF_C1W;
  const bf16* c1bC  = canon + OF_C1B;
  const bf16* gwC   = canon + OF_GW;
  const bf16* gbC   = canon + OF_GB;

  k_detect<<<dim3(1), 256, 0, stream>>>(data, flag);
  k_convert<<<dim3(OF_END / 256), 256, 0, stream>>>(adj, temb, semb, conv1w, conv1b,
                                                    gcnw, gcnb, flag, canon);
  k_wprep<<<dim3(992), 256, 0, stream>>>(c1wC, gwC, Wt, gwT);

  for (int wbase = 0; wbase < NW_; wbase += G) {
    const int gc = (NW_ - wbase < G) ? (NW_ - wbase) : G;

    k_prepg<<<dim3(32, 8, gc + 3), 256, 0, stream>>>(data, flag, tembC, sembC, xg, wbase);

    // wing: Yw = adj[:, :3N] @ x[w..w+3)   (fp32 out)
    k_gemm_adj<0><<<dim3(16, 8, gc), 256, 0, stream>>>(
        adjC, xg, nullptr, Yw, nullptr, nullptr, nullptr, nullptr, 3072, 0, 0);

    for (int j = 0; j < 3; j++) {
      const bf16* Bop = (j == 0) ? (xg + 3 * SLAB_) : curT;
      k_gemm_adj<1><<<dim3(16, 8, gc), 256, 0, stream>>>(
          adjC + 3072, Bop, Yw, nullptr, gwT, gbC, curT, maxT, 1024, j, wbase);
    }

    k_final<<<dim3(8, 32, gc), 256, 0, stream>>>(data, flag, Wt, c1bC, maxT, out, wbase);
  }
}

// Round 5
// 911.736 us; speedup vs baseline: 1.0999x; 1.0062x over previous
//
#include <hip/hip_runtime.h>
#include <cstdint>
#include <cstddef>

// fstgcn on MI355X — round 9:
//  (1) maxT ELIMINATED: layers write bf16 cur0/cur1/cur2 slabs only (12 MiB/w
//      vs 48 MiB/w of fp32 RMW); k_final does the 3-way max (v_max3).
//  (2) wing + layer-0 MERGED: one K=4096 dispatch over full adj; Yw snapshot
//      stored at the k=3072 boundary inside the K-loop; fused zGLU epilogue
//      emits cur0. Kills layer-0's 72 MiB Yw re-read + one launch.
//  (3) FETCH decoded: 117MB = adj x 8 XCDs (64) + xg (48); default x%8 XCD
//      mapping already B-optimal -> no T1 swizzle.

typedef __bf16 bf16;
typedef float f32x4 __attribute__((ext_vector_type(4)));
typedef __bf16 bf16x8 __attribute__((ext_vector_type(8)));
typedef __bf16 bf16x4 __attribute__((ext_vector_type(4)));

constexpr int B_  = 32;
constexpr int T_  = 12;
constexpr int N_  = 1024;
constexpr int C_  = 64;
constexpr int NW_ = 9;
constexpr long long SLAB_ = 2048LL * 1024LL;  // 2M elems: one [bc][n] or [b][n][c] slab

// canonical small-weights block (bf16), element offsets
constexpr int OF_ADJ  = 0;            // 1024*4096
constexpr int OF_TEMB = 4194304;      // 768
constexpr int OF_SEMB = 4195072;      // 65536
constexpr int OF_C1W  = 4260608;      // 32768
constexpr int OF_C1B  = 4293376;      // 128
constexpr int OF_GW   = 4293504;      // 221184
constexpr int OF_GB   = 4514688;      // 3456
constexpr int OF_END  = 4518144;

static __device__ __forceinline__ float sigmoidf_(float x) {
  return __builtin_amdgcn_rcpf(1.0f + __expf(-x));
}

// async global->LDS, 16B per lane; lds ptr must be wave-uniform chunk base
static __device__ __forceinline__ void g2l16(const bf16* g, bf16* l) {
  __builtin_amdgcn_global_load_lds(
      (const __attribute__((address_space(1))) void*)g,
      (__attribute__((address_space(3))) void*)l, 16, 0, 0);
}

// ------------------------------------------------------------ dtype detector (insurance)
__global__ __launch_bounds__(256)
void k_detect(const void* __restrict__ data_raw, int* __restrict__ flag)
{
  __shared__ int cnt;
  const int tid = threadIdx.x;
  if (tid == 0) cnt = 0;
  __syncthreads();
  const uint32_t* W = (const uint32_t*)data_raw;
  int local = 0;
  for (int s = 0; s < 32; s++) {
    const uint32_t w = W[tid * 32 + s];
    const int e8 = (int)((w >> 7) & 0xFF);
    local += (e8 < 97 || e8 > 157) ? 1 : 0;
  }
  atomicAdd(&cnt, local);
  __syncthreads();
  if (tid == 0) *flag = (cnt > 2458) ? 1 : 0;     // >30% weird low-half exponent -> fp32
}

static __device__ __forceinline__ float rd_(const void* p, long long i, int isF32) {
  return isF32 ? ((const float*)p)[i] : (float)((const bf16*)p)[i];
}

// ------------------------------------------------------------ canonicalize weights to bf16
__global__ __launch_bounds__(256)
void k_convert(const void* adj, const void* temb, const void* semb,
               const void* c1w, const void* c1b, const void* gw, const void* gb,
               const int* __restrict__ flagp, bf16* __restrict__ canon)
{
  const int isF32 = *flagp;
  const int e = blockIdx.x * 256 + threadIdx.x;
  float v;
  if      (e < OF_TEMB) v = rd_(adj,  e,           isF32);
  else if (e < OF_SEMB) v = rd_(temb, e - OF_TEMB, isF32);
  else if (e < OF_C1W)  v = rd_(semb, e - OF_SEMB, isF32);
  else if (e < OF_C1B)  v = rd_(c1w,  e - OF_C1W,  isF32);
  else if (e < OF_GW)   v = rd_(c1b,  e - OF_C1B,  isF32);
  else if (e < OF_GB)   v = rd_(gw,   e - OF_GW,   isF32);
  else                  v = rd_(gb,   e - OF_GB,   isF32);
  canon[e] = (bf16)v;
}

// ------------------------------------------------------------ prep x slabs (group)
// xg[s][bc][n] = bf16(data[b][tbase+s][n][c] + temb + semb),  bc = b*64+c
// 32-n strips, semb strip staged in LDS. Grid (32, 8, NS).
__global__ __launch_bounds__(256)
void k_prepg(const void* __restrict__ data_raw, const int* __restrict__ flagp,
             const bf16* __restrict__ temb, const bf16* __restrict__ semb,
             bf16* __restrict__ xg, int tbase)
{
  const int isF32 = *flagp;
  const int s  = blockIdx.z;
  const int t  = tbase + s;
  const int n0 = blockIdx.x * 32;
  const int bc = blockIdx.y * 256 + threadIdx.x;
  const int b = bc >> 6, c = bc & 63;

  __shared__ bf16 lsS[32 * 64];        // semb strip [n 32][c 64]
  *(bf16x8*)&lsS[threadIdx.x * 8] = *(const bf16x8*)&semb[n0 * C_ + threadIdx.x * 8];
  __syncthreads();

  const float te = (float)temb[t * C_ + c];
  const long long dbase = ((long long)(b * T_ + t) * N_ + n0) * C_ + c;
  bf16* op = xg + (size_t)s * SLAB_ + (size_t)bc * N_ + n0;
#pragma unroll
  for (int i = 0; i < 32; i += 8) {
    bf16x8 v;
#pragma unroll
    for (int u = 0; u < 8; u++) {
      const int n = i + u;
      const float dv = rd_(data_raw, dbase + (long long)n * C_, isF32);
      v[u] = (bf16)(dv + te + (float)lsS[n * C_ + c]);
    }
    *(bf16x8*)&op[i] = v;
  }
}

// ------------------------------------------------------------ weight transposes
__global__ __launch_bounds__(256)
void k_wprep(const bf16* __restrict__ conv1w, const bf16* __restrict__ gcnw,
             bf16* __restrict__ Wt, bf16* __restrict__ gwT)
{
  const int idx = blockIdx.x * 256 + threadIdx.x;
  if (idx < 128 * 256) {               // Wt[c2][kidx], kidx = k*64 + ci
    const int c2 = idx >> 8, kidx = idx & 255;
    const int ci = kidx & 63, k = kidx >> 6;
    Wt[idx] = conv1w[c2 * 256 + ci * 4 + k];
  }
  const int i2 = idx - 128 * 256;
  if (i2 >= 0 && i2 < 27 * 8192) {     // gwT[wj][d][c] = gcn_w[wj][c][d]
    const int wj = i2 >> 13, r = i2 & 8191;
    const int d = r >> 6, c = r & 63;
    gwT[i2] = gcnw[wj * 8192 + c * 128 + d];
  }
}

// ------------------------------------------------------------ adjacency GEMM + fused zGLU
// MODE 2 (merged wing+layer0): Aadj = full adj, Ksize=4096, acc init 0,
//        Yw snapshot stored to outF at the k=3072 boundary, epilogue j=0.
// MODE 1 (layer j=1,2): Aadj = adj3, Ksize=1024, acc init = Yw (initY),
//        epilogue j=jlayer.
// Epilogue: t-tile -> LDS (swizzled) -> xW GEMM (K=64) -> +bias -> GLU ->
//           outCur (bf16 slab). No maxT — k_final maxes the 3 slabs.
template<int MODE>
__global__ __launch_bounds__(256)
void k_gemm_adj(const bf16* __restrict__ Aadj, const bf16* __restrict__ Bop,
                const float* __restrict__ initY, float* __restrict__ outF,
                const bf16* __restrict__ gwT, const bf16* __restrict__ gcnb,
                bf16* __restrict__ outCur, int Ksize, int jlayer, int wbase)
{
  const int lw = blockIdx.z;
  const int m0 = blockIdx.y * 128;     // n_out tile
  const int c0 = blockIdx.x * 128;     // bc tile
  const int tid = threadIdx.x;
  const int lane = tid & 63, wid = tid >> 6;
  const int lrow = lane & 15, q = lane >> 4;
  const int wm = wid >> 1, wn = wid & 1;

  // single LDS pool: main loop A dbuf [2][4096] at 0, B dbuf at 8192;
  // fused epilogue reuses all 32 KB as the t tile [m 128][bc 128] bf16.
  __shared__ __align__(16) bf16 lsAll[16384];

  // staging source coords (per-lane constants)
  const int srow = lane >> 2;                                    // row in 16-row chunk
  const int sl_w = ((lane >> 2) & 3) ^ ((lane >> 4) & 3);        // s(row) for writes
  const int skel = ((lane & 3) ^ sl_w) * 8;                      // swizzled src k-elem

  // read-side swizzle (per-lane constant)
  const int sl_r  = (lrow & 3) ^ (lrow >> 2);                    // s(row) for reads
  const int rdoff = ((q ^ sl_r) & 3) * 8;                        // swizzled k-elem in row

  const bf16* Bw = Bop + (size_t)lw * SLAB_;

  auto STAGE = [&](int buf, int k0) {
    const int tblk = k0 >> 10;
    const int kloc = k0 & 1023;
    const bf16* Bt = Bw + (size_t)tblk * SLAB_ + kloc;
    const bf16* At = Aadj + k0;
#pragma unroll
    for (int s = 0; s < 2; s++) {
      const int ch  = s * 4 + wid;               // chunk 0..7 (wave-uniform)
      const int row = ch * 16 + srow;
      g2l16(&At[(size_t)(m0 + row) * 4096 + skel], &lsAll[buf * 4096 + ch * 512]);
      g2l16(&Bt[(size_t)(c0 + row) * N_   + skel], &lsAll[8192 + buf * 4096 + ch * 512]);
    }
  };

  // prologue: stage tile 0; overlap acc init with its latency
  STAGE(0, 0);

  f32x4 acc[4][4];
  const size_t woff = (size_t)lw * SLAB_;
  if (MODE == 1) {
#pragma unroll
    for (int i = 0; i < 4; i++)
#pragma unroll
      for (int jj = 0; jj < 4; jj++) {
        const int col = c0 + wn * 64 + jj * 16 + lrow;
        const int b = col >> 6, c = col & 63;
        const float* yp = initY + woff + (size_t)b * (N_ * C_)
                        + (size_t)(m0 + wm * 64 + i * 16 + q * 4) * C_ + c;
#pragma unroll
        for (int r = 0; r < 4; r++) acc[i][jj][r] = yp[(size_t)r * C_];
      }
  } else {
#pragma unroll
    for (int i = 0; i < 4; i++)
#pragma unroll
      for (int jj = 0; jj < 4; jj++)
#pragma unroll
        for (int r = 0; r < 4; r++) acc[i][jj][r] = 0.0f;
  }

  __syncthreads();

  int cur = 0;
  for (int k0 = 0; k0 < Ksize; k0 += 32) {
    if (k0 + 32 < Ksize) STAGE(cur ^ 1, k0 + 32);

    bf16x8 af[4], bfv[4];
#pragma unroll
    for (int i = 0; i < 4; i++)
      af[i]  = *(const bf16x8*)&lsAll[cur * 4096 + (wm * 64 + i * 16 + lrow) * 32 + rdoff];
#pragma unroll
    for (int jj = 0; jj < 4; jj++)
      bfv[jj] = *(const bf16x8*)&lsAll[8192 + cur * 4096 + (wn * 64 + jj * 16 + lrow) * 32 + rdoff];
#pragma unroll
    for (int i = 0; i < 4; i++)
#pragma unroll
      for (int jj = 0; jj < 4; jj++)
        acc[i][jj] = __builtin_amdgcn_mfma_f32_16x16x32_bf16(af[i], bfv[jj], acc[i][jj], 0, 0, 0);

    // MODE 2: acc now holds the full wing sum (k < 3072) -> snapshot Yw
    if (MODE == 2 && k0 == 3072 - 32) {
#pragma unroll
      for (int i = 0; i < 4; i++)
#pragma unroll
        for (int jj = 0; jj < 4; jj++) {
          const int col = c0 + wn * 64 + jj * 16 + lrow;
          const int b = col >> 6, c = col & 63;
          const size_t base = woff + (size_t)b * (N_ * C_)
                            + (size_t)(m0 + wm * 64 + i * 16 + q * 4) * C_ + c;
#pragma unroll
          for (int r = 0; r < 4; r++) outF[base + (size_t)r * C_] = acc[i][jj][r];
        }
    }

    __syncthreads();
    cur ^= 1;
  }

  // ================= fused epilogue =================
  // t tile [m 128][bc 128] bf16 in LDS. Row = 256 B = 16 slots of 16 B.
  // Swizzle: low-3 slot bits ^= g(row), g(r) = (r ^ (r>>3)) & 7 (bijective,
  // same formula both sides; plain ds ops so rule-21 doesn't apply).
  char* tls = (char*)lsAll;
#pragma unroll
  for (int i = 0; i < 4; i++)
#pragma unroll
    for (int jj = 0; jj < 4; jj++) {
      const int bc = wn * 64 + jj * 16 + lrow;
#pragma unroll
      for (int r = 0; r < 4; r++) {
        const int m = wm * 64 + i * 16 + q * 4 + r;
        const int byte = m * 256 + ((bc * 2) ^ (((m ^ (m >> 3)) & 7) << 4));
        *(bf16*)(tls + byte) = (bf16)acc[i][jj][r];
      }
    }
  __syncthreads();

  const int wj = (wbase + lw) * 3 + jlayer;
  const bf16* Agw  = gwT  + (size_t)wj * 8192;   // [d 128][c 64]
  const bf16* bias = gcnb + (size_t)wj * 128;
  const int nloc0 = wid * 32;                    // per-wave n strip (local)

#pragma unroll
  for (int bl = 0; bl < 2; bl++) {               // two b's in this bc tile
    f32x4 acc2[8][2];
#pragma unroll
    for (int rt = 0; rt < 8; rt++)
#pragma unroll
      for (int ct = 0; ct < 2; ct++)
#pragma unroll
        for (int r = 0; r < 4; r++) acc2[rt][ct][r] = 0.0f;

#pragma unroll
    for (int ks = 0; ks < 2; ks++) {
      bf16x8 bv[2];
#pragma unroll
      for (int ct = 0; ct < 2; ct++) {
        const int nl = nloc0 + ct * 16 + lrow;
        const int byte = nl * 256 +
          (((bl * 64 + ks * 32 + q * 8) * 2) ^ (((nl ^ (nl >> 3)) & 7) << 4));
        bv[ct] = *(const bf16x8*)(tls + byte);
      }
#pragma unroll
      for (int rt = 0; rt < 8; rt++) {
        const bf16x8 av = *(const bf16x8*)&Agw[(rt * 16 + lrow) * 64 + ks * 32 + q * 8];
#pragma unroll
        for (int ct = 0; ct < 2; ct++)
          acc2[rt][ct] = __builtin_amdgcn_mfma_f32_16x16x32_bf16(av, bv[ct], acc2[rt][ct], 0, 0, 0);
      }
    }

    const int bg = (c0 >> 6) + bl;
#pragma unroll
    for (int rt = 0; rt < 4; rt++)
#pragma unroll
      for (int ct = 0; ct < 2; ct++) {
        const int n = m0 + nloc0 + ct * 16 + lrow;
#pragma unroll
        for (int r = 0; r < 4; r++) {
          const int d = rt * 16 + q * 4 + r;
          const float zL = acc2[rt][ct][r]     + (float)bias[d];
          const float zR = acc2[rt + 4][ct][r] + (float)bias[d + 64];
          const float cv = zL * sigmoidf_(zR);
          outCur[woff + (size_t)(bg * 64 + d) * N_ + n] = (bf16)cv;
        }
      }
  }
}

// ------------------------------------------------------------ conv GEMM + GLU + 3-way max
__global__ __launch_bounds__(256)
void k_final(const void* __restrict__ data_raw, const int* __restrict__ flagp,
             const bf16* __restrict__ Wt, const bf16* __restrict__ convb,
             const bf16* __restrict__ cur0, const bf16* __restrict__ cur1,
             const bf16* __restrict__ cur2, float* __restrict__ out, int wbase)
{
  const int isF32 = *flagp;
  const int lw = blockIdx.z;
  const int w = wbase + lw;
  const int bbat = blockIdx.y;
  const int tid = threadIdx.x;
  const int lane = tid & 63, wid = tid >> 6;
  const int lrow = lane & 15, q = lane >> 4;
  const int n0 = blockIdx.x * 128 + wid * 32;

  f32x4 acc[2][8];
#pragma unroll
  for (int rt = 0; rt < 2; rt++)
#pragma unroll
    for (int ct = 0; ct < 8; ct++)
#pragma unroll
      for (int r = 0; r < 4; r++) acc[rt][ct][r] = 0.0f;

#pragma unroll
  for (int s = 0; s < 8; s++) {                 // kidx = s*32 + q*8 + u = k*64 + ci
    const int k = s >> 1, ci0 = (s & 1) * 32;
    bf16x8 av[2];
#pragma unroll
    for (int rt = 0; rt < 2; rt++) {
      const long long off =
        ((long long)((bbat * T_ + w + k) * N_) + n0 + rt * 16 + lrow) * C_ + ci0 + q * 8;
      if (!isF32) {
        av[rt] = *(const bf16x8*)&((const bf16*)data_raw)[off];
      } else {
        const float* p = (const float*)data_raw + off;
        const f32x4 v0 = *(const f32x4*)p;
        const f32x4 v1 = *(const f32x4*)(p + 4);
        bf16x8 v;
#pragma unroll
        for (int u = 0; u < 4; u++) { v[u] = (bf16)v0[u]; v[u + 4] = (bf16)v1[u]; }
        av[rt] = v;
      }
    }
#pragma unroll
    for (int ct = 0; ct < 8; ct++) {
      const bf16x8 bv = *(const bf16x8*)&Wt[(ct * 16 + lrow) * 256 + s * 32 + q * 8];
#pragma unroll
      for (int rt = 0; rt < 2; rt++)
        acc[rt][ct] = __builtin_amdgcn_mfma_f32_16x16x32_bf16(av[rt], bv, acc[rt][ct], 0, 0, 0);
    }
  }

#pragma unroll
  for (int rt = 0; rt < 2; rt++)
#pragma unroll
    for (int ctL = 0; ctL < 4; ctL++) {
      const int cL = ctL * 16 + lrow;
      const float bL = (float)convb[cL], bR = (float)convb[cL + 64];
      const size_t cbase = (size_t)lw * SLAB_ + (size_t)(bbat * 64 + cL) * N_
                         + n0 + rt * 16 + q * 4;
      const bf16x4 m0v = *(const bf16x4*)&cur0[cbase];
      const bf16x4 m1v = *(const bf16x4*)&cur1[cbase];
      const bf16x4 m2v = *(const bf16x4*)&cur2[cbase];
#pragma unroll
      for (int r = 0; r < 4; r++) {
        const int n = n0 + rt * 16 + q * 4 + r;
        const float zL = acc[rt][ctL][r] + bL;
        const float zR = acc[rt][ctL + 4][r] + bR;
        const float res = sigmoidf_(zL) * zR;
        const float mv = fmaxf(fmaxf((float)m0v[r], (float)m1v[r]), (float)m2v[r]);
        out[(size_t)((bbat * NW_ + w) * N_ + n) * C_ + cL] = res + mv;
      }
    }
}

// ------------------------------------------------------------ launcher
extern "C" void kernel_launch(void* const* d_in, const int* in_sizes, int n_in,
                              void* d_out, int out_size, void* d_ws, size_t ws_size,
                              hipStream_t stream)
{
  (void)in_sizes; (void)n_in; (void)out_size;
  const void* data   = d_in[1];
  const void* adj    = d_in[2];
  const void* temb   = d_in[3];
  const void* semb   = d_in[4];
  const void* conv1w = d_in[5];
  const void* conv1b = d_in[6];
  const void* gcnw   = d_in[7];
  const void* gcnb   = d_in[8];
  float* out = (float*)d_out;   // fp32 output per reference dtype

  // footprint(G): canon + xg + Yw + cur(x3) + Wt + gwT
  auto fpn = [&](int g) -> size_t {
    size_t need = 256;
    auto pad = [&](size_t x) { need += (x + 255) & ~(size_t)255; };
    pad((size_t)OF_END * 2);
    pad((size_t)(g + 3) * SLAB_ * 2);     // xg
    pad((size_t)g * SLAB_ * 4);           // Yw (fp32)
    pad((size_t)3 * g * SLAB_ * 2);       // cur0/1/2 (bf16)
    pad(128 * 256 * 2);                   // Wt
    pad(27 * 8192 * 2);                   // gwT
    return need;
  };

  int G = 1;
  for (int g = 9; g >= 2; g--) if (fpn(g) <= ws_size) { G = g; break; }

  char* ws = (char*)d_ws;
  int* flag = (int*)ws;
  size_t off = 256;
  auto allocB = [&](size_t bytes) -> char* {
    char* p = ws + off;
    off += (bytes + 255) & ~(size_t)255;
    return p;
  };
  bf16*  canon = (bf16*) allocB((size_t)OF_END * 2);
  bf16*  xg    = (bf16*) allocB((size_t)(G + 3) * SLAB_ * 2);
  float* Yw    = (float*)allocB((size_t)G * SLAB_ * 4);
  bf16*  curT  = (bf16*) allocB((size_t)3 * G * SLAB_ * 2);
  bf16*  Wt    = (bf16*) allocB(128 * 256 * 2);
  bf16*  gwT   = (bf16*) allocB(27 * 8192 * 2);

  bf16* cur0 = curT;
  bf16* cur1 = curT + (size_t)G * SLAB_;
  bf16* cur2 = curT + (size_t)2 * G * SLAB_;

  const bf16* adjC  = canon + OF_ADJ;
  const bf16* tembC = canon + OF_TEMB;
  const bf16* sembC = canon + OF_SEMB;
  const bf16* c1wC  = canon + OF_C1W;
  const bf16* c1bC  = canon + OF_C1B;
  const bf16* gwC   = canon + OF_GW;
  const bf16* gbC   = canon + OF_GB;

  k_detect<<<dim3(1), 256, 0, stream>>>(data, flag);
  k_convert<<<dim3(OF_END / 256), 256, 0, stream>>>(adj, temb, semb, conv1w, conv1b,
                                                    gcnw, gcnb, flag, canon);
  k_wprep<<<dim3(992), 256, 0, stream>>>(c1wC, gwC, Wt, gwT);

  for (int wbase = 0; wbase < NW_; wbase += G) {
    const int gc = (NW_ - wbase < G) ? (NW_ - wbase) : G;

    k_prepg<<<dim3(32, 8, gc + 3), 256, 0, stream>>>(data, flag, tembC, sembC, xg, wbase);

    // merged wing + layer 0: full adj, K=4096; Yw snapshot + cur0 out
    k_gemm_adj<2><<<dim3(16, 8, gc), 256, 0, stream>>>(
        adjC, xg, nullptr, Yw, gwT, gbC, cur0, 4096, 0, wbase);

    // layers 1,2: adj3 block, K=1024, init Yw
    k_gemm_adj<1><<<dim3(16, 8, gc), 256, 0, stream>>>(
        adjC + 3072, cur0, Yw, nullptr, gwT, gbC, cur1, 1024, 1, wbase);
    k_gemm_adj<1><<<dim3(16, 8, gc), 256, 0, stream>>>(
        adjC + 3072, cur1, Yw, nullptr, gwT, gbC, cur2, 1024, 2, wbase);

    k_final<<<dim3(8, 32, gc), 256, 0, stream>>>(data, flag, Wt, c1bC,
                                                 cur0, cur1, cur2, out, wbase);
  }
}

// Round 6
// 854.159 us; speedup vs baseline: 1.1740x; 1.0674x over previous
//
#include <hip/hip_runtime.h>
#include <cstdint>
#include <cstddef>

// fstgcn on MI355X — round 10:
//  REVERT round-9's wing+layer0 merge (VGPR 56->116, Occ 31->17.5%, VALUBusy
//  16->54% — snapshot branch wrecked regalloc; 324us vs 161+~105 split).
//  KEEP round-9's maxT elimination: layers write bf16 cur0/1/2 slabs, k_final
//  does the 3-way max. This isolates the maxT win the merge masked.

typedef __bf16 bf16;
typedef float f32x4 __attribute__((ext_vector_type(4)));
typedef __bf16 bf16x8 __attribute__((ext_vector_type(8)));
typedef __bf16 bf16x4 __attribute__((ext_vector_type(4)));

constexpr int B_  = 32;
constexpr int T_  = 12;
constexpr int N_  = 1024;
constexpr int C_  = 64;
constexpr int NW_ = 9;
constexpr long long SLAB_ = 2048LL * 1024LL;  // 2M elems: one [bc][n] or [b][n][c] slab

// canonical small-weights block (bf16), element offsets
constexpr int OF_ADJ  = 0;            // 1024*4096
constexpr int OF_TEMB = 4194304;      // 768
constexpr int OF_SEMB = 4195072;      // 65536
constexpr int OF_C1W  = 4260608;      // 32768
constexpr int OF_C1B  = 4293376;      // 128
constexpr int OF_GW   = 4293504;      // 221184
constexpr int OF_GB   = 4514688;      // 3456
constexpr int OF_END  = 4518144;

static __device__ __forceinline__ float sigmoidf_(float x) {
  return __builtin_amdgcn_rcpf(1.0f + __expf(-x));
}

// async global->LDS, 16B per lane; lds ptr must be wave-uniform chunk base
static __device__ __forceinline__ void g2l16(const bf16* g, bf16* l) {
  __builtin_amdgcn_global_load_lds(
      (const __attribute__((address_space(1))) void*)g,
      (__attribute__((address_space(3))) void*)l, 16, 0, 0);
}

// ------------------------------------------------------------ dtype detector (insurance)
__global__ __launch_bounds__(256)
void k_detect(const void* __restrict__ data_raw, int* __restrict__ flag)
{
  __shared__ int cnt;
  const int tid = threadIdx.x;
  if (tid == 0) cnt = 0;
  __syncthreads();
  const uint32_t* W = (const uint32_t*)data_raw;
  int local = 0;
  for (int s = 0; s < 32; s++) {
    const uint32_t w = W[tid * 32 + s];
    const int e8 = (int)((w >> 7) & 0xFF);
    local += (e8 < 97 || e8 > 157) ? 1 : 0;
  }
  atomicAdd(&cnt, local);
  __syncthreads();
  if (tid == 0) *flag = (cnt > 2458) ? 1 : 0;     // >30% weird low-half exponent -> fp32
}

static __device__ __forceinline__ float rd_(const void* p, long long i, int isF32) {
  return isF32 ? ((const float*)p)[i] : (float)((const bf16*)p)[i];
}

// ------------------------------------------------------------ canonicalize weights to bf16
__global__ __launch_bounds__(256)
void k_convert(const void* adj, const void* temb, const void* semb,
               const void* c1w, const void* c1b, const void* gw, const void* gb,
               const int* __restrict__ flagp, bf16* __restrict__ canon)
{
  const int isF32 = *flagp;
  const int e = blockIdx.x * 256 + threadIdx.x;
  float v;
  if      (e < OF_TEMB) v = rd_(adj,  e,           isF32);
  else if (e < OF_SEMB) v = rd_(temb, e - OF_TEMB, isF32);
  else if (e < OF_C1W)  v = rd_(semb, e - OF_SEMB, isF32);
  else if (e < OF_C1B)  v = rd_(c1w,  e - OF_C1W,  isF32);
  else if (e < OF_GW)   v = rd_(c1b,  e - OF_C1B,  isF32);
  else if (e < OF_GB)   v = rd_(gw,   e - OF_GW,   isF32);
  else                  v = rd_(gb,   e - OF_GB,   isF32);
  canon[e] = (bf16)v;
}

// ------------------------------------------------------------ prep x slabs (group)
// xg[s][bc][n] = bf16(data[b][tbase+s][n][c] + temb + semb),  bc = b*64+c
// 32-n strips, semb strip staged in LDS. Grid (32, 8, NS).
__global__ __launch_bounds__(256)
void k_prepg(const void* __restrict__ data_raw, const int* __restrict__ flagp,
             const bf16* __restrict__ temb, const bf16* __restrict__ semb,
             bf16* __restrict__ xg, int tbase)
{
  const int isF32 = *flagp;
  const int s  = blockIdx.z;
  const int t  = tbase + s;
  const int n0 = blockIdx.x * 32;
  const int bc = blockIdx.y * 256 + threadIdx.x;
  const int b = bc >> 6, c = bc & 63;

  __shared__ bf16 lsS[32 * 64];        // semb strip [n 32][c 64]
  *(bf16x8*)&lsS[threadIdx.x * 8] = *(const bf16x8*)&semb[n0 * C_ + threadIdx.x * 8];
  __syncthreads();

  const float te = (float)temb[t * C_ + c];
  const long long dbase = ((long long)(b * T_ + t) * N_ + n0) * C_ + c;
  bf16* op = xg + (size_t)s * SLAB_ + (size_t)bc * N_ + n0;
#pragma unroll
  for (int i = 0; i < 32; i += 8) {
    bf16x8 v;
#pragma unroll
    for (int u = 0; u < 8; u++) {
      const int n = i + u;
      const float dv = rd_(data_raw, dbase + (long long)n * C_, isF32);
      v[u] = (bf16)(dv + te + (float)lsS[n * C_ + c]);
    }
    *(bf16x8*)&op[i] = v;
  }
}

// ------------------------------------------------------------ weight transposes
__global__ __launch_bounds__(256)
void k_wprep(const bf16* __restrict__ conv1w, const bf16* __restrict__ gcnw,
             bf16* __restrict__ Wt, bf16* __restrict__ gwT)
{
  const int idx = blockIdx.x * 256 + threadIdx.x;
  if (idx < 128 * 256) {               // Wt[c2][kidx], kidx = k*64 + ci
    const int c2 = idx >> 8, kidx = idx & 255;
    const int ci = kidx & 63, k = kidx >> 6;
    Wt[idx] = conv1w[c2 * 256 + ci * 4 + k];
  }
  const int i2 = idx - 128 * 256;
  if (i2 >= 0 && i2 < 27 * 8192) {     // gwT[wj][d][c] = gcn_w[wj][c][d]
    const int wj = i2 >> 13, r = i2 & 8191;
    const int d = r >> 6, c = r & 63;
    gwT[i2] = gcnw[wj * 8192 + c * 128 + d];
  }
}

// ------------------------------------------------------------ adjacency GEMM
// MODE 0 (wing):  init 0,       store fp32 -> outF (Yw), return (no epilogue)
// MODE 1 (layer): init fp32 Yw, FUSED epilogue: t-tile -> LDS -> xW GEMM
//                 (K=64) -> +bias -> GLU -> outCur (bf16 slab).
template<int MODE>
__global__ __launch_bounds__(256)
void k_gemm_adj(const bf16* __restrict__ Aadj, const bf16* __restrict__ Bop,
                const float* __restrict__ initY, float* __restrict__ outF,
                const bf16* __restrict__ gwT, const bf16* __restrict__ gcnb,
                bf16* __restrict__ outCur, int Ksize, int jlayer, int wbase)
{
  const int lw = blockIdx.z;
  const int m0 = blockIdx.y * 128;     // n_out tile
  const int c0 = blockIdx.x * 128;     // bc tile
  const int tid = threadIdx.x;
  const int lane = tid & 63, wid = tid >> 6;
  const int lrow = lane & 15, q = lane >> 4;
  const int wm = wid >> 1, wn = wid & 1;

  // single LDS pool: main loop A dbuf [2][4096] at 0, B dbuf at 8192;
  // fused epilogue reuses all 32 KB as the t tile [m 128][bc 128] bf16.
  __shared__ __align__(16) bf16 lsAll[16384];

  // staging source coords (per-lane constants)
  const int srow = lane >> 2;                                    // row in 16-row chunk
  const int sl_w = ((lane >> 2) & 3) ^ ((lane >> 4) & 3);        // s(row) for writes
  const int skel = ((lane & 3) ^ sl_w) * 8;                      // swizzled src k-elem

  // read-side swizzle (per-lane constant)
  const int sl_r  = (lrow & 3) ^ (lrow >> 2);                    // s(row) for reads
  const int rdoff = ((q ^ sl_r) & 3) * 8;                        // swizzled k-elem in row

  const bf16* Bw = Bop + (size_t)lw * SLAB_;

  auto STAGE = [&](int buf, int k0) {
    const int tblk = k0 >> 10;
    const int kloc = k0 & 1023;
    const bf16* Bt = Bw + (size_t)tblk * SLAB_ + kloc;
    const bf16* At = Aadj + k0;
#pragma unroll
    for (int s = 0; s < 2; s++) {
      const int ch  = s * 4 + wid;               // chunk 0..7 (wave-uniform)
      const int row = ch * 16 + srow;
      g2l16(&At[(size_t)(m0 + row) * 4096 + skel], &lsAll[buf * 4096 + ch * 512]);
      g2l16(&Bt[(size_t)(c0 + row) * N_   + skel], &lsAll[8192 + buf * 4096 + ch * 512]);
    }
  };

  // prologue: stage tile 0; overlap acc init with its latency
  STAGE(0, 0);

  f32x4 acc[4][4];
  const size_t woff = (size_t)lw * SLAB_;
  if (MODE == 1) {
#pragma unroll
    for (int i = 0; i < 4; i++)
#pragma unroll
      for (int jj = 0; jj < 4; jj++) {
        const int col = c0 + wn * 64 + jj * 16 + lrow;
        const int b = col >> 6, c = col & 63;
        const float* yp = initY + woff + (size_t)b * (N_ * C_)
                        + (size_t)(m0 + wm * 64 + i * 16 + q * 4) * C_ + c;
#pragma unroll
        for (int r = 0; r < 4; r++) acc[i][jj][r] = yp[(size_t)r * C_];
      }
  } else {
#pragma unroll
    for (int i = 0; i < 4; i++)
#pragma unroll
      for (int jj = 0; jj < 4; jj++)
#pragma unroll
        for (int r = 0; r < 4; r++) acc[i][jj][r] = 0.0f;
  }

  __syncthreads();

  int cur = 0;
  for (int k0 = 0; k0 < Ksize; k0 += 32) {
    if (k0 + 32 < Ksize) STAGE(cur ^ 1, k0 + 32);

    bf16x8 af[4], bfv[4];
#pragma unroll
    for (int i = 0; i < 4; i++)
      af[i]  = *(const bf16x8*)&lsAll[cur * 4096 + (wm * 64 + i * 16 + lrow) * 32 + rdoff];
#pragma unroll
    for (int jj = 0; jj < 4; jj++)
      bfv[jj] = *(const bf16x8*)&lsAll[8192 + cur * 4096 + (wn * 64 + jj * 16 + lrow) * 32 + rdoff];
#pragma unroll
    for (int i = 0; i < 4; i++)
#pragma unroll
      for (int jj = 0; jj < 4; jj++)
        acc[i][jj] = __builtin_amdgcn_mfma_f32_16x16x32_bf16(af[i], bfv[jj], acc[i][jj], 0, 0, 0);

    __syncthreads();
    cur ^= 1;
  }

  if (MODE == 0) {
#pragma unroll
    for (int i = 0; i < 4; i++)
#pragma unroll
      for (int jj = 0; jj < 4; jj++) {
        const int col = c0 + wn * 64 + jj * 16 + lrow;
        const int b = col >> 6, c = col & 63;
        const size_t base = woff + (size_t)b * (N_ * C_)
                          + (size_t)(m0 + wm * 64 + i * 16 + q * 4) * C_ + c;
#pragma unroll
        for (int r = 0; r < 4; r++) outF[base + (size_t)r * C_] = acc[i][jj][r];
      }
    return;
  }

  // ================= fused epilogue (MODE 1) =================
  // t tile [m 128][bc 128] bf16 in LDS. Row = 256 B = 16 slots of 16 B.
  // Swizzle: low-3 slot bits ^= g(row), g(r) = (r ^ (r>>3)) & 7 (bijective,
  // same formula both sides; plain ds ops so rule-21 doesn't apply).
  char* tls = (char*)lsAll;
#pragma unroll
  for (int i = 0; i < 4; i++)
#pragma unroll
    for (int jj = 0; jj < 4; jj++) {
      const int bc = wn * 64 + jj * 16 + lrow;
#pragma unroll
      for (int r = 0; r < 4; r++) {
        const int m = wm * 64 + i * 16 + q * 4 + r;
        const int byte = m * 256 + ((bc * 2) ^ (((m ^ (m >> 3)) & 7) << 4));
        *(bf16*)(tls + byte) = (bf16)acc[i][jj][r];
      }
    }
  __syncthreads();

  const int wj = (wbase + lw) * 3 + jlayer;
  const bf16* Agw  = gwT  + (size_t)wj * 8192;   // [d 128][c 64]
  const bf16* bias = gcnb + (size_t)wj * 128;
  const int nloc0 = wid * 32;                    // per-wave n strip (local)

#pragma unroll
  for (int bl = 0; bl < 2; bl++) {               // two b's in this bc tile
    f32x4 acc2[8][2];
#pragma unroll
    for (int rt = 0; rt < 8; rt++)
#pragma unroll
      for (int ct = 0; ct < 2; ct++)
#pragma unroll
        for (int r = 0; r < 4; r++) acc2[rt][ct][r] = 0.0f;

#pragma unroll
    for (int ks = 0; ks < 2; ks++) {
      bf16x8 bv[2];
#pragma unroll
      for (int ct = 0; ct < 2; ct++) {
        const int nl = nloc0 + ct * 16 + lrow;
        const int byte = nl * 256 +
          (((bl * 64 + ks * 32 + q * 8) * 2) ^ (((nl ^ (nl >> 3)) & 7) << 4));
        bv[ct] = *(const bf16x8*)(tls + byte);
      }
#pragma unroll
      for (int rt = 0; rt < 8; rt++) {
        const bf16x8 av = *(const bf16x8*)&Agw[(rt * 16 + lrow) * 64 + ks * 32 + q * 8];
#pragma unroll
        for (int ct = 0; ct < 2; ct++)
          acc2[rt][ct] = __builtin_amdgcn_mfma_f32_16x16x32_bf16(av, bv[ct], acc2[rt][ct], 0, 0, 0);
      }
    }

    const int bg = (c0 >> 6) + bl;
#pragma unroll
    for (int rt = 0; rt < 4; rt++)
#pragma unroll
      for (int ct = 0; ct < 2; ct++) {
        const int n = m0 + nloc0 + ct * 16 + lrow;
#pragma unroll
        for (int r = 0; r < 4; r++) {
          const int d = rt * 16 + q * 4 + r;
          const float zL = acc2[rt][ct][r]     + (float)bias[d];
          const float zR = acc2[rt + 4][ct][r] + (float)bias[d + 64];
          const float cv = zL * sigmoidf_(zR);
          outCur[woff + (size_t)(bg * 64 + d) * N_ + n] = (bf16)cv;
        }
      }
  }
}

// ------------------------------------------------------------ conv GEMM + GLU + 3-way max
__global__ __launch_bounds__(256)
void k_final(const void* __restrict__ data_raw, const int* __restrict__ flagp,
             const bf16* __restrict__ Wt, const bf16* __restrict__ convb,
             const bf16* __restrict__ cur0, const bf16* __restrict__ cur1,
             const bf16* __restrict__ cur2, float* __restrict__ out, int wbase)
{
  const int isF32 = *flagp;
  const int lw = blockIdx.z;
  const int w = wbase + lw;
  const int bbat = blockIdx.y;
  const int tid = threadIdx.x;
  const int lane = tid & 63, wid = tid >> 6;
  const int lrow = lane & 15, q = lane >> 4;
  const int n0 = blockIdx.x * 128 + wid * 32;

  f32x4 acc[2][8];
#pragma unroll
  for (int rt = 0; rt < 2; rt++)
#pragma unroll
    for (int ct = 0; ct < 8; ct++)
#pragma unroll
      for (int r = 0; r < 4; r++) acc[rt][ct][r] = 0.0f;

#pragma unroll
  for (int s = 0; s < 8; s++) {                 // kidx = s*32 + q*8 + u = k*64 + ci
    const int k = s >> 1, ci0 = (s & 1) * 32;
    bf16x8 av[2];
#pragma unroll
    for (int rt = 0; rt < 2; rt++) {
      const long long off =
        ((long long)((bbat * T_ + w + k) * N_) + n0 + rt * 16 + lrow) * C_ + ci0 + q * 8;
      if (!isF32) {
        av[rt] = *(const bf16x8*)&((const bf16*)data_raw)[off];
      } else {
        const float* p = (const float*)data_raw + off;
        const f32x4 v0 = *(const f32x4*)p;
        const f32x4 v1 = *(const f32x4*)(p + 4);
        bf16x8 v;
#pragma unroll
        for (int u = 0; u < 4; u++) { v[u] = (bf16)v0[u]; v[u + 4] = (bf16)v1[u]; }
        av[rt] = v;
      }
    }
#pragma unroll
    for (int ct = 0; ct < 8; ct++) {
      const bf16x8 bv = *(const bf16x8*)&Wt[(ct * 16 + lrow) * 256 + s * 32 + q * 8];
#pragma unroll
      for (int rt = 0; rt < 2; rt++)
        acc[rt][ct] = __builtin_amdgcn_mfma_f32_16x16x32_bf16(av[rt], bv, acc[rt][ct], 0, 0, 0);
    }
  }

#pragma unroll
  for (int rt = 0; rt < 2; rt++)
#pragma unroll
    for (int ctL = 0; ctL < 4; ctL++) {
      const int cL = ctL * 16 + lrow;
      const float bL = (float)convb[cL], bR = (float)convb[cL + 64];
      const size_t cbase = (size_t)lw * SLAB_ + (size_t)(bbat * 64 + cL) * N_
                         + n0 + rt * 16 + q * 4;
      const bf16x4 m0v = *(const bf16x4*)&cur0[cbase];
      const bf16x4 m1v = *(const bf16x4*)&cur1[cbase];
      const bf16x4 m2v = *(const bf16x4*)&cur2[cbase];
#pragma unroll
      for (int r = 0; r < 4; r++) {
        const int n = n0 + rt * 16 + q * 4 + r;
        const float zL = acc[rt][ctL][r] + bL;
        const float zR = acc[rt][ctL + 4][r] + bR;
        const float res = sigmoidf_(zL) * zR;
        const float mv = fmaxf(fmaxf((float)m0v[r], (float)m1v[r]), (float)m2v[r]);
        out[(size_t)((bbat * NW_ + w) * N_ + n) * C_ + cL] = res + mv;
      }
    }
}

// ------------------------------------------------------------ launcher
extern "C" void kernel_launch(void* const* d_in, const int* in_sizes, int n_in,
                              void* d_out, int out_size, void* d_ws, size_t ws_size,
                              hipStream_t stream)
{
  (void)in_sizes; (void)n_in; (void)out_size;
  const void* data   = d_in[1];
  const void* adj    = d_in[2];
  const void* temb   = d_in[3];
  const void* semb   = d_in[4];
  const void* conv1w = d_in[5];
  const void* conv1b = d_in[6];
  const void* gcnw   = d_in[7];
  const void* gcnb   = d_in[8];
  float* out = (float*)d_out;   // fp32 output per reference dtype

  // footprint(G): canon + xg + Yw + cur(x3) + Wt + gwT
  auto fpn = [&](int g) -> size_t {
    size_t need = 256;
    auto pad = [&](size_t x) { need += (x + 255) & ~(size_t)255; };
    pad((size_t)OF_END * 2);
    pad((size_t)(g + 3) * SLAB_ * 2);     // xg
    pad((size_t)g * SLAB_ * 4);           // Yw (fp32)
    pad((size_t)3 * g * SLAB_ * 2);       // cur0/1/2 (bf16)
    pad(128 * 256 * 2);                   // Wt
    pad(27 * 8192 * 2);                   // gwT
    return need;
  };

  int G = 1;
  for (int g = 9; g >= 2; g--) if (fpn(g) <= ws_size) { G = g; break; }

  char* ws = (char*)d_ws;
  int* flag = (int*)ws;
  size_t off = 256;
  auto allocB = [&](size_t bytes) -> char* {
    char* p = ws + off;
    off += (bytes + 255) & ~(size_t)255;
    return p;
  };
  bf16*  canon = (bf16*) allocB((size_t)OF_END * 2);
  bf16*  xg    = (bf16*) allocB((size_t)(G + 3) * SLAB_ * 2);
  float* Yw    = (float*)allocB((size_t)G * SLAB_ * 4);
  bf16*  curT  = (bf16*) allocB((size_t)3 * G * SLAB_ * 2);
  bf16*  Wt    = (bf16*) allocB(128 * 256 * 2);
  bf16*  gwT   = (bf16*) allocB(27 * 8192 * 2);

  bf16* cur0 = curT;
  bf16* cur1 = curT + (size_t)G * SLAB_;
  bf16* cur2 = curT + (size_t)2 * G * SLAB_;

  const bf16* adjC  = canon + OF_ADJ;
  const bf16* tembC = canon + OF_TEMB;
  const bf16* sembC = canon + OF_SEMB;
  const bf16* c1wC  = canon + OF_C1W;
  const bf16* c1bC  = canon + OF_C1B;
  const bf16* gwC   = canon + OF_GW;
  const bf16* gbC   = canon + OF_GB;

  k_detect<<<dim3(1), 256, 0, stream>>>(data, flag);
  k_convert<<<dim3(OF_END / 256), 256, 0, stream>>>(adj, temb, semb, conv1w, conv1b,
                                                    gcnw, gcnb, flag, canon);
  k_wprep<<<dim3(992), 256, 0, stream>>>(c1wC, gwC, Wt, gwT);

  for (int wbase = 0; wbase < NW_; wbase += G) {
    const int gc = (NW_ - wbase < G) ? (NW_ - wbase) : G;

    k_prepg<<<dim3(32, 8, gc + 3), 256, 0, stream>>>(data, flag, tembC, sembC, xg, wbase);

    // wing: Yw = adj[:, :3N] @ x[w..w+3)   (fp32 out, no epilogue)
    k_gemm_adj<0><<<dim3(16, 8, gc), 256, 0, stream>>>(
        adjC, xg, nullptr, Yw, nullptr, nullptr, nullptr, 3072, 0, 0);

    // layers 0,1,2: adj3 block, K=1024, init Yw, fused zGLU -> cur slab
    k_gemm_adj<1><<<dim3(16, 8, gc), 256, 0, stream>>>(
        adjC + 3072, xg + 3 * SLAB_, Yw, nullptr, gwT, gbC, cur0, 1024, 0, wbase);
    k_gemm_adj<1><<<dim3(16, 8, gc), 256, 0, stream>>>(
        adjC + 3072, cur0, Yw, nullptr, gwT, gbC, cur1, 1024, 1, wbase);
    k_gemm_adj<1><<<dim3(16, 8, gc), 256, 0, stream>>>(
        adjC + 3072, cur1, Yw, nullptr, gwT, gbC, cur2, 1024, 2, wbase);

    k_final<<<dim3(8, 32, gc), 256, 0, stream>>>(data, flag, Wt, c1bC,
                                                 cur0, cur1, cur2, out, wbase);
  }
}

// Round 8
// 749.708 us; speedup vs baseline: 1.3376x; 1.1393x over previous
//
#include <hip/hip_runtime.h>
#include <cstdint>
#include <cstddef>

// fstgcn on MI355X — round 12 (= round 11 resubmitted; container infra failure,
// source re-audited: LDS 48KB ok, YwT bounds ok, swizzle bijective, no
// divergent barriers — no kernel-side fault vector found):
//  (1) k_final persistent-window: block = (b, 32-n strip); all 12 timesteps
//      staged ONCE in LDS (48KB bf16, XOR swizzle vs 128B-row conflict);
//      Wt fragments hoisted; loop 9 windows in-block. Round-10 counters:
//      k_final 161us, MfmaUtil 4.5%, 4x redundant fp32 re-reads.
//  (2) Yw transposed to [bc][n] fp32: wing stores f32x4, layer inits f32x4.

typedef __bf16 bf16;
typedef float f32x4 __attribute__((ext_vector_type(4)));
typedef __bf16 bf16x8 __attribute__((ext_vector_type(8)));
typedef __bf16 bf16x4 __attribute__((ext_vector_type(4)));

constexpr int B_  = 32;
constexpr int T_  = 12;
constexpr int N_  = 1024;
constexpr int C_  = 64;
constexpr int NW_ = 9;
constexpr long long SLAB_ = 2048LL * 1024LL;  // 2M elems: one [bc][n] or [b][n][c] slab

// canonical small-weights block (bf16), element offsets
constexpr int OF_ADJ  = 0;            // 1024*4096
constexpr int OF_TEMB = 4194304;      // 768
constexpr int OF_SEMB = 4195072;      // 65536
constexpr int OF_C1W  = 4260608;      // 32768
constexpr int OF_C1B  = 4293376;      // 128
constexpr int OF_GW   = 4293504;      // 221184
constexpr int OF_GB   = 4514688;      // 3456
constexpr int OF_END  = 4518144;

static __device__ __forceinline__ float sigmoidf_(float x) {
  return __builtin_amdgcn_rcpf(1.0f + __expf(-x));
}

// async global->LDS, 16B per lane; lds ptr must be wave-uniform chunk base
static __device__ __forceinline__ void g2l16(const bf16* g, bf16* l) {
  __builtin_amdgcn_global_load_lds(
      (const __attribute__((address_space(1))) void*)g,
      (__attribute__((address_space(3))) void*)l, 16, 0, 0);
}

// ------------------------------------------------------------ dtype detector (insurance)
__global__ __launch_bounds__(256)
void k_detect(const void* __restrict__ data_raw, int* __restrict__ flag)
{
  __shared__ int cnt;
  const int tid = threadIdx.x;
  if (tid == 0) cnt = 0;
  __syncthreads();
  const uint32_t* W = (const uint32_t*)data_raw;
  int local = 0;
  for (int s = 0; s < 32; s++) {
    const uint32_t w = W[tid * 32 + s];
    const int e8 = (int)((w >> 7) & 0xFF);
    local += (e8 < 97 || e8 > 157) ? 1 : 0;
  }
  atomicAdd(&cnt, local);
  __syncthreads();
  if (tid == 0) *flag = (cnt > 2458) ? 1 : 0;     // >30% weird low-half exponent -> fp32
}

static __device__ __forceinline__ float rd_(const void* p, long long i, int isF32) {
  return isF32 ? ((const float*)p)[i] : (float)((const bf16*)p)[i];
}

// ------------------------------------------------------------ canonicalize weights to bf16
__global__ __launch_bounds__(256)
void k_convert(const void* adj, const void* temb, const void* semb,
               const void* c1w, const void* c1b, const void* gw, const void* gb,
               const int* __restrict__ flagp, bf16* __restrict__ canon)
{
  const int isF32 = *flagp;
  const int e = blockIdx.x * 256 + threadIdx.x;
  float v;
  if      (e < OF_TEMB) v = rd_(adj,  e,           isF32);
  else if (e < OF_SEMB) v = rd_(temb, e - OF_TEMB, isF32);
  else if (e < OF_C1W)  v = rd_(semb, e - OF_SEMB, isF32);
  else if (e < OF_C1B)  v = rd_(c1w,  e - OF_C1W,  isF32);
  else if (e < OF_GW)   v = rd_(c1b,  e - OF_C1B,  isF32);
  else if (e < OF_GB)   v = rd_(gw,   e - OF_GW,   isF32);
  else                  v = rd_(gb,   e - OF_GB,   isF32);
  canon[e] = (bf16)v;
}

// ------------------------------------------------------------ prep x slabs (group)
// xg[s][bc][n] = bf16(data[b][tbase+s][n][c] + temb + semb),  bc = b*64+c
__global__ __launch_bounds__(256)
void k_prepg(const void* __restrict__ data_raw, const int* __restrict__ flagp,
             const bf16* __restrict__ temb, const bf16* __restrict__ semb,
             bf16* __restrict__ xg, int tbase)
{
  const int isF32 = *flagp;
  const int s  = blockIdx.z;
  const int t  = tbase + s;
  const int n0 = blockIdx.x * 32;
  const int bc = blockIdx.y * 256 + threadIdx.x;
  const int b = bc >> 6, c = bc & 63;

  __shared__ bf16 lsS[32 * 64];        // semb strip [n 32][c 64]
  *(bf16x8*)&lsS[threadIdx.x * 8] = *(const bf16x8*)&semb[n0 * C_ + threadIdx.x * 8];
  __syncthreads();

  const float te = (float)temb[t * C_ + c];
  const long long dbase = ((long long)(b * T_ + t) * N_ + n0) * C_ + c;
  bf16* op = xg + (size_t)s * SLAB_ + (size_t)bc * N_ + n0;
#pragma unroll
  for (int i = 0; i < 32; i += 8) {
    bf16x8 v;
#pragma unroll
    for (int u = 0; u < 8; u++) {
      const int n = i + u;
      const float dv = rd_(data_raw, dbase + (long long)n * C_, isF32);
      v[u] = (bf16)(dv + te + (float)lsS[n * C_ + c]);
    }
    *(bf16x8*)&op[i] = v;
  }
}

// ------------------------------------------------------------ weight transposes
__global__ __launch_bounds__(256)
void k_wprep(const bf16* __restrict__ conv1w, const bf16* __restrict__ gcnw,
             bf16* __restrict__ Wt, bf16* __restrict__ gwT)
{
  const int idx = blockIdx.x * 256 + threadIdx.x;
  if (idx < 128 * 256) {               // Wt[c2][kidx], kidx = k*64 + ci
    const int c2 = idx >> 8, kidx = idx & 255;
    const int ci = kidx & 63, k = kidx >> 6;
    Wt[idx] = conv1w[c2 * 256 + ci * 4 + k];
  }
  const int i2 = idx - 128 * 256;
  if (i2 >= 0 && i2 < 27 * 8192) {     // gwT[wj][d][c] = gcn_w[wj][c][d]
    const int wj = i2 >> 13, r = i2 & 8191;
    const int d = r >> 6, c = r & 63;
    gwT[i2] = gcnw[wj * 8192 + c * 128 + d];
  }
}

// ------------------------------------------------------------ adjacency GEMM
// MODE 0 (wing):  init 0,       store fp32 -> outF = YwT[bc][n], no epilogue
// MODE 1 (layer): init fp32 YwT, FUSED epilogue: t-tile -> LDS -> xW GEMM
//                 (K=64) -> +bias -> GLU -> outCur (bf16 slab).
template<int MODE>
__global__ __launch_bounds__(256)
void k_gemm_adj(const bf16* __restrict__ Aadj, const bf16* __restrict__ Bop,
                const float* __restrict__ initY, float* __restrict__ outF,
                const bf16* __restrict__ gwT, const bf16* __restrict__ gcnb,
                bf16* __restrict__ outCur, int Ksize, int jlayer, int wbase)
{
  const int lw = blockIdx.z;
  const int m0 = blockIdx.y * 128;     // n_out tile
  const int c0 = blockIdx.x * 128;     // bc tile
  const int tid = threadIdx.x;
  const int lane = tid & 63, wid = tid >> 6;
  const int lrow = lane & 15, q = lane >> 4;
  const int wm = wid >> 1, wn = wid & 1;

  // single LDS pool: main loop A dbuf [2][4096] at 0, B dbuf at 8192;
  // fused epilogue reuses all 32 KB as the t tile [m 128][bc 128] bf16.
  __shared__ __align__(16) bf16 lsAll[16384];

  // staging source coords (per-lane constants)
  const int srow = lane >> 2;                                    // row in 16-row chunk
  const int sl_w = ((lane >> 2) & 3) ^ ((lane >> 4) & 3);        // s(row) for writes
  const int skel = ((lane & 3) ^ sl_w) * 8;                      // swizzled src k-elem

  // read-side swizzle (per-lane constant)
  const int sl_r  = (lrow & 3) ^ (lrow >> 2);                    // s(row) for reads
  const int rdoff = ((q ^ sl_r) & 3) * 8;                        // swizzled k-elem in row

  const bf16* Bw = Bop + (size_t)lw * SLAB_;

  auto STAGE = [&](int buf, int k0) {
    const int tblk = k0 >> 10;
    const int kloc = k0 & 1023;
    const bf16* Bt = Bw + (size_t)tblk * SLAB_ + kloc;
    const bf16* At = Aadj + k0;
#pragma unroll
    for (int s = 0; s < 2; s++) {
      const int ch  = s * 4 + wid;               // chunk 0..7 (wave-uniform)
      const int row = ch * 16 + srow;
      g2l16(&At[(size_t)(m0 + row) * 4096 + skel], &lsAll[buf * 4096 + ch * 512]);
      g2l16(&Bt[(size_t)(c0 + row) * N_   + skel], &lsAll[8192 + buf * 4096 + ch * 512]);
    }
  };

  // prologue: stage tile 0; overlap acc init with its latency
  STAGE(0, 0);

  f32x4 acc[4][4];
  const size_t woff = (size_t)lw * SLAB_;
  if (MODE == 1) {
#pragma unroll
    for (int i = 0; i < 4; i++)
#pragma unroll
      for (int jj = 0; jj < 4; jj++) {
        const int col = c0 + wn * 64 + jj * 16 + lrow;
        const int m = m0 + wm * 64 + i * 16 + q * 4;
        acc[i][jj] = *(const f32x4*)&initY[woff + (size_t)col * N_ + m];
      }
  } else {
#pragma unroll
    for (int i = 0; i < 4; i++)
#pragma unroll
      for (int jj = 0; jj < 4; jj++)
#pragma unroll
        for (int r = 0; r < 4; r++) acc[i][jj][r] = 0.0f;
  }

  __syncthreads();

  int cur = 0;
  for (int k0 = 0; k0 < Ksize; k0 += 32) {
    if (k0 + 32 < Ksize) STAGE(cur ^ 1, k0 + 32);

    bf16x8 af[4], bfv[4];
#pragma unroll
    for (int i = 0; i < 4; i++)
      af[i]  = *(const bf16x8*)&lsAll[cur * 4096 + (wm * 64 + i * 16 + lrow) * 32 + rdoff];
#pragma unroll
    for (int jj = 0; jj < 4; jj++)
      bfv[jj] = *(const bf16x8*)&lsAll[8192 + cur * 4096 + (wn * 64 + jj * 16 + lrow) * 32 + rdoff];
#pragma unroll
    for (int i = 0; i < 4; i++)
#pragma unroll
      for (int jj = 0; jj < 4; jj++)
        acc[i][jj] = __builtin_amdgcn_mfma_f32_16x16x32_bf16(af[i], bfv[jj], acc[i][jj], 0, 0, 0);

    __syncthreads();
    cur ^= 1;
  }

  if (MODE == 0) {
#pragma unroll
    for (int i = 0; i < 4; i++)
#pragma unroll
      for (int jj = 0; jj < 4; jj++) {
        const int col = c0 + wn * 64 + jj * 16 + lrow;
        const int m = m0 + wm * 64 + i * 16 + q * 4;
        *(f32x4*)&outF[woff + (size_t)col * N_ + m] = acc[i][jj];
      }
    return;
  }

  // ================= fused epilogue (MODE 1) =================
  // t tile [m 128][bc 128] bf16 in LDS. Row = 256 B = 16 slots of 16 B.
  // Swizzle: low-3 slot bits ^= g(row), g(r) = (r ^ (r>>3)) & 7.
  char* tls = (char*)lsAll;
#pragma unroll
  for (int i = 0; i < 4; i++)
#pragma unroll
    for (int jj = 0; jj < 4; jj++) {
      const int bc = wn * 64 + jj * 16 + lrow;
#pragma unroll
      for (int r = 0; r < 4; r++) {
        const int m = wm * 64 + i * 16 + q * 4 + r;
        const int byte = m * 256 + ((bc * 2) ^ (((m ^ (m >> 3)) & 7) << 4));
        *(bf16*)(tls + byte) = (bf16)acc[i][jj][r];
      }
    }
  __syncthreads();

  const int wj = (wbase + lw) * 3 + jlayer;
  const bf16* Agw  = gwT  + (size_t)wj * 8192;   // [d 128][c 64]
  const bf16* bias = gcnb + (size_t)wj * 128;
  const int nloc0 = wid * 32;                    // per-wave n strip (local)

#pragma unroll
  for (int bl = 0; bl < 2; bl++) {               // two b's in this bc tile
    f32x4 acc2[8][2];
#pragma unroll
    for (int rt = 0; rt < 8; rt++)
#pragma unroll
      for (int ct = 0; ct < 2; ct++)
#pragma unroll
        for (int r = 0; r < 4; r++) acc2[rt][ct][r] = 0.0f;

#pragma unroll
    for (int ks = 0; ks < 2; ks++) {
      bf16x8 bv[2];
#pragma unroll
      for (int ct = 0; ct < 2; ct++) {
        const int nl = nloc0 + ct * 16 + lrow;
        const int byte = nl * 256 +
          (((bl * 64 + ks * 32 + q * 8) * 2) ^ (((nl ^ (nl >> 3)) & 7) << 4));
        bv[ct] = *(const bf16x8*)(tls + byte);
      }
#pragma unroll
      for (int rt = 0; rt < 8; rt++) {
        const bf16x8 av = *(const bf16x8*)&Agw[(rt * 16 + lrow) * 64 + ks * 32 + q * 8];
#pragma unroll
        for (int ct = 0; ct < 2; ct++)
          acc2[rt][ct] = __builtin_amdgcn_mfma_f32_16x16x32_bf16(av, bv[ct], acc2[rt][ct], 0, 0, 0);
      }
    }

    const int bg = (c0 >> 6) + bl;
#pragma unroll
    for (int rt = 0; rt < 4; rt++)
#pragma unroll
      for (int ct = 0; ct < 2; ct++) {
        const int n = m0 + nloc0 + ct * 16 + lrow;
#pragma unroll
        for (int r = 0; r < 4; r++) {
          const int d = rt * 16 + q * 4 + r;
          const float zL = acc2[rt][ct][r]     + (float)bias[d];
          const float zR = acc2[rt + 4][ct][r] + (float)bias[d + 64];
          const float cv = zL * sigmoidf_(zR);
          outCur[woff + (size_t)(bg * 64 + d) * N_ + n] = (bf16)cv;
        }
      }
  }
}

// ------------------------------------------------------------ persistent-window conv + GLU + 3-way max
// block = (b, 32-n strip); stage data[b][0..11][n0..n0+32][c] once in LDS
// (bf16, XOR swizzle byte^=(n&7)<<4); hoist Wt frags; loop gc windows.
__global__ __launch_bounds__(256)
void k_final(const void* __restrict__ data_raw, const int* __restrict__ flagp,
             const bf16* __restrict__ Wt, const bf16* __restrict__ convb,
             const bf16* __restrict__ cur0, const bf16* __restrict__ cur1,
             const bf16* __restrict__ cur2, float* __restrict__ out,
             int wbase, int gc)
{
  const int isF32 = *flagp;
  const int b  = blockIdx.y;
  const int n0 = blockIdx.x * 32;
  const int tid = threadIdx.x;
  const int lane = tid & 63, wid = tid >> 6;
  const int lrow = lane & 15, q = lane >> 4;

  __shared__ __align__(16) bf16 lsD[T_ * 32 * C_];   // 48 KB, [t][n][c] swizzled

  // ---- stage all 12 timesteps of this (b, n-strip), bf16-convert ----
#pragma unroll
  for (int it = 0; it < 6; it++) {
    const int idx  = it * 256 + tid;       // 0..1535
    const int row  = idx >> 2;             // t*32 + n, 0..383
    const int part = idx & 3;              // 16-c chunk
    const int t = row >> 5, n = row & 31;
    const long long goff = ((long long)(b * T_ + t) * N_ + n0 + n) * C_ + part * 16;
    bf16x8 h0, h1;
    if (isF32) {
      const float* p = (const float*)data_raw + goff;
      const f32x4 v0 = *(const f32x4*)p,      v1 = *(const f32x4*)(p + 4);
      const f32x4 v2 = *(const f32x4*)(p + 8), v3 = *(const f32x4*)(p + 12);
#pragma unroll
      for (int u = 0; u < 4; u++) {
        h0[u] = (bf16)v0[u]; h0[u + 4] = (bf16)v1[u];
        h1[u] = (bf16)v2[u]; h1[u + 4] = (bf16)v3[u];
      }
    } else {
      const bf16* p = (const bf16*)data_raw + goff;
      h0 = *(const bf16x8*)p;
      h1 = *(const bf16x8*)(p + 8);
    }
    const int base = row * 128 + part * 32;
    const int swz  = (n & 7) << 4;
    *(bf16x8*)((char*)lsD + (base ^ swz))        = h0;
    *(bf16x8*)((char*)lsD + ((base + 16) ^ swz)) = h1;
  }

  // ---- hoist Wt fragments (same for all windows): wave owns c2 tiles {wid, wid+4}
  bf16x8 bvL[8], bvR[8];
#pragma unroll
  for (int s = 0; s < 8; s++) {
    bvL[s] = *(const bf16x8*)&Wt[(wid * 16 + lrow) * 256 + s * 32 + q * 8];
    bvR[s] = *(const bf16x8*)&Wt[((wid + 4) * 16 + lrow) * 256 + s * 32 + q * 8];
  }
  const int cL = wid * 16 + lrow;
  const float bL = (float)convb[cL], bR = (float)convb[cL + 64];

  __syncthreads();

  for (int wl = 0; wl < gc; wl++) {
    const int w = wbase + wl;
    f32x4 acc[2][2];
#pragma unroll
    for (int rt = 0; rt < 2; rt++)
#pragma unroll
      for (int ct = 0; ct < 2; ct++)
#pragma unroll
        for (int r = 0; r < 4; r++) acc[rt][ct][r] = 0.0f;

#pragma unroll
    for (int s = 0; s < 8; s++) {               // kidx = s*32 + q*8 .. ; k = s>>1
      const int t = w + (s >> 1), ci0 = (s & 1) * 32;
      bf16x8 av[2];
#pragma unroll
      for (int rt = 0; rt < 2; rt++) {
        const int n = rt * 16 + lrow;
        const int byte = ((t * 32 + n) * 128 + (ci0 + q * 8) * 2) ^ ((n & 7) << 4);
        av[rt] = *(const bf16x8*)((const char*)lsD + byte);
      }
#pragma unroll
      for (int rt = 0; rt < 2; rt++) {
        acc[rt][0] = __builtin_amdgcn_mfma_f32_16x16x32_bf16(av[rt], bvL[s], acc[rt][0], 0, 0, 0);
        acc[rt][1] = __builtin_amdgcn_mfma_f32_16x16x32_bf16(av[rt], bvR[s], acc[rt][1], 0, 0, 0);
      }
    }

#pragma unroll
    for (int rt = 0; rt < 2; rt++) {
      const size_t cbase = (size_t)wl * SLAB_ + (size_t)(b * 64 + cL) * N_
                         + n0 + rt * 16 + q * 4;
      const bf16x4 m0v = *(const bf16x4*)&cur0[cbase];
      const bf16x4 m1v = *(const bf16x4*)&cur1[cbase];
      const bf16x4 m2v = *(const bf16x4*)&cur2[cbase];
#pragma unroll
      for (int r = 0; r < 4; r++) {
        const int n = n0 + rt * 16 + q * 4 + r;
        const float zL = acc[rt][0][r] + bL;
        const float zR = acc[rt][1][r] + bR;
        const float res = sigmoidf_(zL) * zR;
        const float mv = fmaxf(fmaxf((float)m0v[r], (float)m1v[r]), (float)m2v[r]);
        out[(size_t)((b * NW_ + w) * N_ + n) * C_ + cL] = res + mv;
      }
    }
  }
}

// ------------------------------------------------------------ launcher
extern "C" void kernel_launch(void* const* d_in, const int* in_sizes, int n_in,
                              void* d_out, int out_size, void* d_ws, size_t ws_size,
                              hipStream_t stream)
{
  (void)in_sizes; (void)n_in; (void)out_size;
  const void* data   = d_in[1];
  const void* adj    = d_in[2];
  const void* temb   = d_in[3];
  const void* semb   = d_in[4];
  const void* conv1w = d_in[5];
  const void* conv1b = d_in[6];
  const void* gcnw   = d_in[7];
  const void* gcnb   = d_in[8];
  float* out = (float*)d_out;   // fp32 output per reference dtype

  // footprint(G): canon + xg + Yw + cur(x3) + Wt + gwT
  auto fpn = [&](int g) -> size_t {
    size_t need = 256;
    auto pad = [&](size_t x) { need += (x + 255) & ~(size_t)255; };
    pad((size_t)OF_END * 2);
    pad((size_t)(g + 3) * SLAB_ * 2);     // xg
    pad((size_t)g * SLAB_ * 4);           // YwT (fp32, [bc][n])
    pad((size_t)3 * g * SLAB_ * 2);       // cur0/1/2 (bf16)
    pad(128 * 256 * 2);                   // Wt
    pad(27 * 8192 * 2);                   // gwT
    return need;
  };

  int G = 1;
  for (int g = 9; g >= 2; g--) if (fpn(g) <= ws_size) { G = g; break; }

  char* ws = (char*)d_ws;
  int* flag = (int*)ws;
  size_t off = 256;
  auto allocB = [&](size_t bytes) -> char* {
    char* p = ws + off;
    off += (bytes + 255) & ~(size_t)255;
    return p;
  };
  bf16*  canon = (bf16*) allocB((size_t)OF_END * 2);
  bf16*  xg    = (bf16*) allocB((size_t)(G + 3) * SLAB_ * 2);
  float* Yw    = (float*)allocB((size_t)G * SLAB_ * 4);
  bf16*  curT  = (bf16*) allocB((size_t)3 * G * SLAB_ * 2);
  bf16*  Wt    = (bf16*) allocB(128 * 256 * 2);
  bf16*  gwT   = (bf16*) allocB(27 * 8192 * 2);

  bf16* cur0 = curT;
  bf16* cur1 = curT + (size_t)G * SLAB_;
  bf16* cur2 = curT + (size_t)2 * G * SLAB_;

  const bf16* adjC  = canon + OF_ADJ;
  const bf16* tembC = canon + OF_TEMB;
  const bf16* sembC = canon + OF_SEMB;
  const bf16* c1wC  = canon + OF_C1W;
  const bf16* c1bC  = canon + OF_C1B;
  const bf16* gwC   = canon + OF_GW;
  const bf16* gbC   = canon + OF_GB;

  k_detect<<<dim3(1), 256, 0, stream>>>(data, flag);
  k_convert<<<dim3(OF_END / 256), 256, 0, stream>>>(adj, temb, semb, conv1w, conv1b,
                                                    gcnw, gcnb, flag, canon);
  k_wprep<<<dim3(992), 256, 0, stream>>>(c1wC, gwC, Wt, gwT);

  for (int wbase = 0; wbase < NW_; wbase += G) {
    const int gc = (NW_ - wbase < G) ? (NW_ - wbase) : G;

    k_prepg<<<dim3(32, 8, gc + 3), 256, 0, stream>>>(data, flag, tembC, sembC, xg, wbase);

    // wing: YwT = (adj[:, :3N] @ x[w..w+3))^T   (fp32 [bc][n], no epilogue)
    k_gemm_adj<0><<<dim3(16, 8, gc), 256, 0, stream>>>(
        adjC, xg, nullptr, Yw, nullptr, nullptr, nullptr, 3072, 0, 0);

    // layers 0,1,2: adj3 block, K=1024, init YwT, fused zGLU -> cur slab
    k_gemm_adj<1><<<dim3(16, 8, gc), 256, 0, stream>>>(
        adjC + 3072, xg + 3 * SLAB_, Yw, nullptr, gwT, gbC, cur0, 1024, 0, wbase);
    k_gemm_adj<1><<<dim3(16, 8, gc), 256, 0, stream>>>(
        adjC + 3072, cur0, Yw, nullptr, gwT, gbC, cur1, 1024, 1, wbase);
    k_gemm_adj<1><<<dim3(16, 8, gc), 256, 0, stream>>>(
        adjC + 3072, cur1, Yw, nullptr, gwT, gbC, cur2, 1024, 2, wbase);

    k_final<<<dim3(32, 32, 1), 256, 0, stream>>>(data, flag, Wt, c1bC,
                                                 cur0, cur1, cur2, out, wbase, gc);
  }
}